// Round 4
// baseline (66742.908 us; speedup 1.0000x reference)
//
#include <hip/hip_runtime.h>
#include <math.h>

#define NB   8
#define NC   512
#define SP   4096
#define TOT  16777216L
static const double PI_D = 3.14159265358979323846;

typedef short s16x8 __attribute__((ext_vector_type(8)));
typedef float f32x4 __attribute__((ext_vector_type(4)));
typedef unsigned short u16;

// ---------------- ws layout (float units) ----------------
// region A [0,16777216): t fp32; then hist19 (4x512K u32 = 2M u32); then h1pre+X2 bf16
// region B [16777216,25165824): thi/tlo bf16; later h1 bf16
// region C [25165824,41943040): D fp32; later h2 bf16 in first half
#define OFF_T    0L
#define OFF_H19  0L
#define OFF_H1P  0L
#define OFF_X2   8388608L
#define OFF_THI  16777216L
#define OFF_TLO  20971520L
#define OFF_H1   16777216L
#define OFF_D    25165824L
#define OFF_H2   25165824L
#define OFF_AK   41943040L
#define OFF_AKH  42205184L
#define OFF_AKL  42336256L
#define OFF_ACT  42467328L
#define OFF_GBF  42468352L
#define OFF_W2A  42599424L
#define OFF_W3B  42894336L
#define OFF_HIST 42927104L            // hist1 4096 (u32)
#define OFF_SEL  42937344L            // u32[16]
#define OFF_THR  42937360L            // float[4]
#define OFF_AC   42937368L

__device__ inline u16 bfr(float x) {
    unsigned u = __float_as_uint(x);
    unsigned r = u + 0x7fffu + ((u >> 16) & 1u);
    return (u16)(r >> 16);
}
__device__ inline float bff(u16 h) { return __uint_as_float(((unsigned)h) << 16); }

#define MFMA(a, b, c) __builtin_amdgcn_mfma_f32_16x16x32_bf16((a), (b), (c), 0, 0, 0)

// ---------------- setup kernels ----------------
__global__ void k_build_mats(float* __restrict__ Ak, u16* __restrict__ Akh, u16* __restrict__ Akl,
                             u16* __restrict__ AcT, float* __restrict__ Ac) {
    int idx = blockIdx.x * 256 + threadIdx.x;
    if (idx < 512 * 512) {
        int i = idx >> 9, j = idx & 511;
        double v = cos((double)i * ((double)j + 0.5) * (PI_D / 512.0)) * sqrt(2.0 / 512.0);
        if (i == 0) v *= (1.0 / sqrt(2.0));
        float f = (float)v;
        Ak[idx] = f;
        u16 h = bfr(f);
        Akh[idx] = h;
        Akl[idx] = bfr(f - bff(h));
    }
    if (idx < 64 * 64) {
        int i = idx >> 6, j = idx & 63;
        double v = cos((double)i * ((double)j + 0.5) * (PI_D / 64.0)) * sqrt(2.0 / 64.0);
        if (i == 0) v *= (1.0 / sqrt(2.0));
        Ac[idx] = (float)v;
        int n = idx >> 6, np = idx & 63;
        double w = cos((double)np * ((double)n + 0.5) * (PI_D / 64.0)) * sqrt(2.0 / 64.0);
        if (np == 0) w *= (1.0 / sqrt(2.0));
        AcT[idx] = bfr((float)w);
    }
}

__global__ void k_zero(unsigned* __restrict__ p, int n) {
    int i = blockIdx.x * 256 + threadIdx.x;
    if (i < n) p[i] = 0u;
}

__global__ void k_zero19(uint4* __restrict__ p) {
    // 2M u32 = 512K uint4; grid 2048 x 256
    p[blockIdx.x * 256 + threadIdx.x] = make_uint4(0u, 0u, 0u, 0u);
}

// G_bf[i][o][kc] = bf16( sum_c W1[i][o][c] * Ak[kc][c] )
__global__ void k_G_bf(const float* __restrict__ W1, const float* __restrict__ Ak,
                       u16* __restrict__ G) {
    int idx = blockIdx.x * 256 + threadIdx.x;
    int kc = idx & 511, oi = idx >> 9;
    const float* w = W1 + (long)oi * 512;
    const float* a = Ak + (long)kc * 512;
    float s = 0.f;
    for (int c = 0; c < 512; ++c) s += w[c] * a[c];
    G[idx] = bfr(s);
}

// W2a[i][o][t*128+ci] = W2[i][o][ci][t];  W3b = cvt(W3)
__global__ void k_wprep(const float* __restrict__ W2, const float* __restrict__ W3,
                        u16* __restrict__ W2a, u16* __restrict__ W3b) {
    int idx = blockIdx.x * 256 + threadIdx.x;
    if (idx < 4 * 128 * 1152) {
        int k = idx % 1152;
        int oi = idx / 1152;
        int t = k >> 7, ci = k & 127;
        W2a[idx] = bfr(W2[((long)oi * 128 + ci) * 9 + t]);
    }
    if (idx < 65536) W3b[idx] = bfr(W3[idx]);
}

// ---------------- forward 2D DCT tile (fp32) ----------------
__global__ __launch_bounds__(256) void k_tile_fwd(const float* __restrict__ in,
                                                  float* __restrict__ out,
                                                  const float* __restrict__ A64) {
    __shared__ __align__(16) float Ms[64][68];
    __shared__ __align__(16) float Ts[64][68];
    __shared__ __align__(16) float Ss[64][68];
    const int tid = threadIdx.x;
    const long tile = blockIdx.x;
    const float* __restrict__ src = in + tile * 4096;
    float* __restrict__ dst = out + tile * 4096;
    for (int idx = tid; idx < 4096; idx += 256) {
        int r = idx >> 6, c = idx & 63;
        Ms[c][r] = A64[idx];
        Ts[r][c] = src[idx];
    }
    __syncthreads();
    const int tx = tid & 15, ty = tid >> 4;
    float acc[4][4];
#pragma unroll
    for (int i = 0; i < 4; ++i)
#pragma unroll
        for (int j = 0; j < 4; ++j) acc[i][j] = 0.f;
#pragma unroll 4
    for (int j = 0; j < 64; ++j) {
        float4 bv = *(const float4*)&Ms[j][tx * 4];
        float a0 = Ts[ty * 4 + 0][j], a1 = Ts[ty * 4 + 1][j];
        float a2 = Ts[ty * 4 + 2][j], a3 = Ts[ty * 4 + 3][j];
        acc[0][0] += a0 * bv.x; acc[0][1] += a0 * bv.y; acc[0][2] += a0 * bv.z; acc[0][3] += a0 * bv.w;
        acc[1][0] += a1 * bv.x; acc[1][1] += a1 * bv.y; acc[1][2] += a1 * bv.z; acc[1][3] += a1 * bv.w;
        acc[2][0] += a2 * bv.x; acc[2][1] += a2 * bv.y; acc[2][2] += a2 * bv.z; acc[2][3] += a2 * bv.w;
        acc[3][0] += a3 * bv.x; acc[3][1] += a3 * bv.y; acc[3][2] += a3 * bv.z; acc[3][3] += a3 * bv.w;
    }
#pragma unroll
    for (int i = 0; i < 4; ++i)
        *(float4*)&Ss[ty * 4 + i][tx * 4] = make_float4(acc[i][0], acc[i][1], acc[i][2], acc[i][3]);
    __syncthreads();
#pragma unroll
    for (int i = 0; i < 4; ++i)
#pragma unroll
        for (int j = 0; j < 4; ++j) acc[i][j] = 0.f;
#pragma unroll 4
    for (int j = 0; j < 64; ++j) {
        float4 av = *(const float4*)&Ms[j][ty * 4];
        float4 sv = *(const float4*)&Ss[j][tx * 4];
        acc[0][0] += av.x * sv.x; acc[0][1] += av.x * sv.y; acc[0][2] += av.x * sv.z; acc[0][3] += av.x * sv.w;
        acc[1][0] += av.y * sv.x; acc[1][1] += av.y * sv.y; acc[1][2] += av.y * sv.z; acc[1][3] += av.y * sv.w;
        acc[2][0] += av.z * sv.x; acc[2][1] += av.z * sv.y; acc[2][2] += av.z * sv.z; acc[2][3] += av.z * sv.w;
        acc[3][0] += av.w * sv.x; acc[3][1] += av.w * sv.y; acc[3][2] += av.w * sv.z; acc[3][3] += av.w * sv.w;
    }
#pragma unroll
    for (int i = 0; i < 4; ++i)
        *(float4*)&dst[(ty * 4 + i) * 64 + tx * 4] = make_float4(acc[i][0], acc[i][1], acc[i][2], acc[i][3]);
}

// ---------------- transpose + split: t NCHW fp32 -> thi/tlo NHWC bf16 ----------------
__global__ __launch_bounds__(256) void k_tsplit(const float* __restrict__ t,
                                                u16* __restrict__ thi, u16* __restrict__ tlo) {
    __shared__ float Ls[64][65];
    const int b = blockIdx.z, cg = blockIdx.y, pg = blockIdx.x;
    const int tid = threadIdx.x;
    const float* src = t + ((long)b * 512 + cg * 64) * 4096 + pg * 64;
#pragma unroll
    for (int j = 0; j < 4; ++j) {
        int c = (tid >> 4) + j * 16, p4 = (tid & 15) * 4;
        float4 v = *(const float4*)&src[(long)c * 4096 + p4];
        Ls[c][p4 + 0] = v.x; Ls[c][p4 + 1] = v.y; Ls[c][p4 + 2] = v.z; Ls[c][p4 + 3] = v.w;
    }
    __syncthreads();
#pragma unroll
    for (int j = 0; j < 2; ++j) {
        int idx = tid + j * 256;
        int p = idx >> 3, c8 = idx & 7;
        s16x8 vh, vl;
#pragma unroll
        for (int q = 0; q < 8; ++q) {
            float f = Ls[c8 * 8 + q][p];
            u16 h = bfr(f);
            vh[q] = (short)h;
            vl[q] = (short)bfr(f - bff(h));
        }
        long addr = ((long)b * 4096 + pg * 64 + p) * 512 + cg * 64 + c8 * 8;
        *(s16x8*)&thi[addr] = vh;
        *(s16x8*)&tlo[addr] = vl;
    }
}

// ---------------- C-DCT GEMM + fused hist1 ----------------
__global__ __launch_bounds__(256, 2) void k_cgemm(const u16* __restrict__ thi, const u16* __restrict__ tlo,
                                                  const u16* __restrict__ Akh, const u16* __restrict__ Akl,
                                                  float* __restrict__ D, unsigned* __restrict__ g1) {
    __shared__ __align__(16) short Ph[128 * 40];
    __shared__ __align__(16) short Pl[128 * 40];
    __shared__ __align__(16) short Qh[128 * 40];
    __shared__ __align__(16) short Ql[128 * 40];
    __shared__ unsigned hh[4096];
    const int b = blockIdx.z;
    const int p0 = blockIdx.y * 128, kc0 = blockIdx.x * 128;
    const int tid = threadIdx.x;
    const int lane = tid & 63, wave = tid >> 6;
    const int fr = lane & 15, qd = lane >> 4;
    const int mq = (wave >> 1) * 64, nq = (wave & 1) * 64;
    for (int t = tid; t < 4096; t += 256) hh[t] = 0u;
    f32x4 acc[4][4];
#pragma unroll
    for (int i = 0; i < 4; ++i)
#pragma unroll
        for (int j = 0; j < 4; ++j) acc[i][j] = (f32x4){0.f, 0.f, 0.f, 0.f};
    const u16* Pgh = thi + ((long)b * 4096 + p0) * 512;
    const u16* Pgl = tlo + ((long)b * 4096 + p0) * 512;
    const u16* Qgh = Akh + (long)kc0 * 512;
    const u16* Qgl = Akl + (long)kc0 * 512;
    for (int ch = 0; ch < 16; ++ch) {
        const int k0 = ch * 32;
        __syncthreads();
#pragma unroll
        for (int j = 0; j < 2; ++j) {
            int idx = tid + j * 256;
            int r = idx >> 2, q4 = (idx & 3) * 8;
            *(s16x8*)&Ph[r * 40 + q4] = *(const s16x8*)&Pgh[(long)r * 512 + k0 + q4];
            *(s16x8*)&Pl[r * 40 + q4] = *(const s16x8*)&Pgl[(long)r * 512 + k0 + q4];
            *(s16x8*)&Qh[r * 40 + q4] = *(const s16x8*)&Qgh[(long)r * 512 + k0 + q4];
            *(s16x8*)&Ql[r * 40 + q4] = *(const s16x8*)&Qgl[(long)r * 512 + k0 + q4];
        }
        __syncthreads();
        s16x8 ph[4], pl[4], qh[4], ql[4];
#pragma unroll
        for (int i = 0; i < 4; ++i) {
            ph[i] = *(const s16x8*)&Ph[(mq + 16 * i + fr) * 40 + qd * 8];
            pl[i] = *(const s16x8*)&Pl[(mq + 16 * i + fr) * 40 + qd * 8];
            qh[i] = *(const s16x8*)&Qh[(nq + 16 * i + fr) * 40 + qd * 8];
            ql[i] = *(const s16x8*)&Ql[(nq + 16 * i + fr) * 40 + qd * 8];
        }
#pragma unroll
        for (int i = 0; i < 4; ++i)
#pragma unroll
            for (int j = 0; j < 4; ++j) {
                acc[i][j] = MFMA(ph[i], qh[j], acc[i][j]);
                acc[i][j] = MFMA(ph[i], ql[j], acc[i][j]);
                acc[i][j] = MFMA(pl[i], qh[j], acc[i][j]);
            }
    }
#pragma unroll
    for (int i = 0; i < 4; ++i)
#pragma unroll
        for (int j = 0; j < 4; ++j) {
            int rowb = mq + 16 * i + qd * 4;
            int col = kc0 + nq + 16 * j + fr;
#pragma unroll
            for (int r = 0; r < 4; ++r) {
                float v = acc[i][j][r];
                D[((long)b * 4096 + p0 + rowb + r) * 512 + col] = v;
                atomicAdd(&hh[__float_as_uint(fabsf(v)) >> 19], 1u);
            }
        }
    __syncthreads();
    for (int t = tid; t < 4096; t += 256) {
        unsigned c = hh[t];
        if (c) atomicAdd(&g1[t], c);
    }
}

// ---------------- selection: scan1 -> hist19 -> scan19 ----------------
__global__ void k_scan1(const unsigned* __restrict__ hist, unsigned* __restrict__ sel) {
    __shared__ unsigned chunk[256];
    __shared__ unsigned above[256];
    const int t = threadIdx.x;
    unsigned s = 0;
#pragma unroll
    for (int j = 0; j < 16; ++j) s += hist[t * 16 + j];
    chunk[t] = s;
    __syncthreads();
    if (t == 0) {
        unsigned a = 0;
        for (int c = 255; c >= 0; --c) { above[c] = a; a += chunk[c]; }
    }
    __syncthreads();
    const unsigned kv[4] = {4194304u, 1048576u, 262144u, 65536u};
    unsigned run = above[t];
    for (int j = 15; j >= 0; --j) {
        unsigned bin = t * 16 + j;
        unsigned hb = hist[bin];
        unsigned Sab = run;
        run += hb;
#pragma unroll
        for (int i = 0; i < 4; ++i)
            if (run >= kv[i] && Sab < kv[i]) { sel[i] = bin; sel[4 + i] = kv[i] - Sab; }
    }
}

// one pass over D: histogram low-19 bits of elements matching any selected prefix
__global__ __launch_bounds__(256) void k_hist19(const float4* __restrict__ D,
                                                const unsigned* __restrict__ sel,
                                                unsigned* __restrict__ g) {
    const unsigned p0 = sel[0], p1 = sel[1], p2 = sel[2], p3 = sel[3];
    const long n4 = TOT / 4;
    for (long idx = (long)blockIdx.x * 256 + threadIdx.x; idx < n4; idx += (long)gridDim.x * 256) {
        float4 v = D[idx];
        float f[4] = {v.x, v.y, v.z, v.w};
#pragma unroll
        for (int q = 0; q < 4; ++q) {
            unsigned u = __float_as_uint(fabsf(f[q]));
            unsigned pre = u >> 19, low = u & 0x7FFFFu;
            if (pre == p0) atomicAdd(&g[low], 1u);
            if (pre == p1) atomicAdd(&g[524288u + low], 1u);
            if (pre == p2) atomicAdd(&g[1048576u + low], 1u);
            if (pre == p3) atomicAdd(&g[1572864u + low], 1u);
        }
    }
}

// per list: find bin where descending cumulative crosses r -> exact threshold bits
__global__ __launch_bounds__(1024) void k_scan19(const unsigned* __restrict__ hist,
                                                 const unsigned* __restrict__ sel,
                                                 float* __restrict__ thr) {
    __shared__ unsigned csum[1024];
    __shared__ unsigned above[1024];
    const int i = blockIdx.x;
    const unsigned* h = hist + (long)i * 524288;
    const unsigned r = sel[4 + i];
    const int t = threadIdx.x;
    unsigned s = 0;
    const uint4* h4 = (const uint4*)(h + t * 512);
#pragma unroll 8
    for (int j = 0; j < 128; ++j) {
        uint4 v = h4[j];
        s += v.x + v.y + v.z + v.w;
    }
    csum[t] = s;
    __syncthreads();
    if (t == 0) {
        unsigned a = 0;
        for (int c = 1023; c >= 0; --c) { above[c] = a; a += csum[c]; }
    }
    __syncthreads();
    const unsigned Sab = above[t];
    if (r > Sab && r <= Sab + csum[t]) {
        unsigned run = Sab;
        for (int j = 511; j >= 0; --j) {
            unsigned hb = h[t * 512 + j];
            unsigned prev = run;
            run += hb;
            if (run >= r && prev < r)
                thr[i] = __uint_as_float((sel[i] << 19) | (unsigned)(t * 512 + j));
        }
    }
}

// ---------------- conv1 fused with IDCT_C ----------------
__global__ __launch_bounds__(256, 2) void k_conv1(const float* __restrict__ D, const u16* __restrict__ Gb,
                                                  const float* __restrict__ thrp, u16* __restrict__ h1pre) {
    __shared__ __align__(16) short Pt[128 * 40];
    __shared__ __align__(16) short Qt[128 * 40];
    const int b = blockIdx.z, br = blockIdx.y, p0 = blockIdx.x * 128;
    const int z2 = br * 8 + b;
    const float thr = thrp[br];
    const int tid = threadIdx.x;
    const int lane = tid & 63, wave = tid >> 6;
    const int fr = lane & 15, qd = lane >> 4;
    const int mq = (wave >> 1) * 64, nq = (wave & 1) * 64;
    f32x4 acc[4][4];
#pragma unroll
    for (int i = 0; i < 4; ++i)
#pragma unroll
        for (int j = 0; j < 4; ++j) acc[i][j] = (f32x4){0.f, 0.f, 0.f, 0.f};
    const float* Pg = D + ((long)b * 4096 + p0) * 512;
    const u16* Qg = Gb + (long)br * 65536;
    for (int ch = 0; ch < 16; ++ch) {
        const int k0 = ch * 32;
        __syncthreads();
#pragma unroll
        for (int j = 0; j < 2; ++j) {
            int idx = tid + j * 256;
            int r = idx >> 2, q4 = (idx & 3) * 8;
            const float* src = &Pg[(long)r * 512 + k0 + q4];
            float4 v0 = *(const float4*)src;
            float4 v1 = *(const float4*)(src + 4);
            s16x8 m;
            float f[8] = {v0.x, v0.y, v0.z, v0.w, v1.x, v1.y, v1.z, v1.w};
#pragma unroll
            for (int q = 0; q < 8; ++q) m[q] = (short)(fabsf(f[q]) >= thr ? bfr(f[q]) : (u16)0);
            *(s16x8*)&Pt[r * 40 + q4] = m;
            *(s16x8*)&Qt[r * 40 + q4] = *(const s16x8*)&Qg[(long)r * 512 + k0 + q4];
        }
        __syncthreads();
        s16x8 pa[4], qb[4];
#pragma unroll
        for (int i = 0; i < 4; ++i) {
            pa[i] = *(const s16x8*)&Pt[(mq + 16 * i + fr) * 40 + qd * 8];
            qb[i] = *(const s16x8*)&Qt[(nq + 16 * i + fr) * 40 + qd * 8];
        }
#pragma unroll
        for (int i = 0; i < 4; ++i)
#pragma unroll
            for (int j = 0; j < 4; ++j) acc[i][j] = MFMA(pa[i], qb[j], acc[i][j]);
    }
#pragma unroll
    for (int i = 0; i < 4; ++i)
#pragma unroll
        for (int j = 0; j < 4; ++j) {
            int rowb = p0 + mq + 16 * i + qd * 4;
            int o = nq + 16 * j + fr;
            ushort4 pk;
            pk.x = bfr(acc[i][j][0]); pk.y = bfr(acc[i][j][1]);
            pk.z = bfr(acc[i][j][2]); pk.w = bfr(acc[i][j][3]);
            *(ushort4*)&h1pre[((long)z2 * 128 + o) * 4096 + rowb] = pk;
        }
}

// ---------------- IDCT passes ----------------
__global__ __launch_bounds__(256, 2) void k_idct1(const u16* __restrict__ h1pre, const u16* __restrict__ AcT,
                                                  u16* __restrict__ X2) {
    __shared__ __align__(16) short Pt[128 * 72];
    __shared__ __align__(16) short Qt[64 * 72];
    const int b = blockIdx.z, br = blockIdx.y, m0 = blockIdx.x * 128;
    const int z2 = br * 8 + b;
    const int tid = threadIdx.x;
    const int lane = tid & 63, wave = tid >> 6;
    const int fr = lane & 15, qd = lane >> 4;
    const int mq = wave * 32;
    const u16* Pg = h1pre + (long)z2 * 524288 + (long)m0 * 64;
    f32x4 acc[2][4];
#pragma unroll
    for (int i = 0; i < 2; ++i)
#pragma unroll
        for (int j = 0; j < 4; ++j) acc[i][j] = (f32x4){0.f, 0.f, 0.f, 0.f};
#pragma unroll
    for (int j = 0; j < 4; ++j) {
        int idx = tid + j * 256;
        int r = idx >> 3, q8 = (idx & 7) * 8;
        *(s16x8*)&Pt[r * 72 + q8] = *(const s16x8*)&Pg[(long)r * 64 + q8];
    }
#pragma unroll
    for (int j = 0; j < 2; ++j) {
        int idx = tid + j * 256;
        int r = idx >> 3, q8 = (idx & 7) * 8;
        *(s16x8*)&Qt[r * 72 + q8] = *(const s16x8*)&AcT[(long)r * 64 + q8];
    }
    __syncthreads();
#pragma unroll
    for (int ks = 0; ks < 2; ++ks) {
        s16x8 pa[2], qb[4];
#pragma unroll
        for (int i = 0; i < 2; ++i) pa[i] = *(const s16x8*)&Pt[(mq + 16 * i + fr) * 72 + ks * 32 + qd * 8];
#pragma unroll
        for (int j = 0; j < 4; ++j) qb[j] = *(const s16x8*)&Qt[(16 * j + fr) * 72 + ks * 32 + qd * 8];
#pragma unroll
        for (int i = 0; i < 2; ++i)
#pragma unroll
            for (int j = 0; j < 4; ++j) acc[i][j] = MFMA(pa[i], qb[j], acc[i][j]);
    }
#pragma unroll
    for (int i = 0; i < 2; ++i)
#pragma unroll
        for (int j = 0; j < 4; ++j) {
            int Rb = m0 + mq + 16 * i + qd * 4;
            int o = Rb >> 6, y = Rb & 63;
            int xo = 16 * j + fr;
            ushort4 pk;
            pk.x = bfr(acc[i][j][0]); pk.y = bfr(acc[i][j][1]);
            pk.z = bfr(acc[i][j][2]); pk.w = bfr(acc[i][j][3]);
            *(ushort4*)&X2[(long)z2 * 524288 + ((long)xo * 128 + o) * 64 + y] = pk;
        }
}

__global__ __launch_bounds__(256, 2) void k_idct2(const u16* __restrict__ X2, const u16* __restrict__ AcT,
                                                  const float* __restrict__ b1, u16* __restrict__ h1) {
    __shared__ __align__(16) short Pt[128 * 72];
    __shared__ __align__(16) short Qt[64 * 72];
    const int b = blockIdx.z, br = blockIdx.y, m0 = blockIdx.x * 128;
    const int z2 = br * 8 + b;
    const int tid = threadIdx.x;
    const int lane = tid & 63, wave = tid >> 6;
    const int fr = lane & 15, qd = lane >> 4;
    const int mq = wave * 32;
    const u16* Pg = X2 + (long)z2 * 524288 + (long)m0 * 64;
    f32x4 acc[2][4];
#pragma unroll
    for (int i = 0; i < 2; ++i)
#pragma unroll
        for (int j = 0; j < 4; ++j) acc[i][j] = (f32x4){0.f, 0.f, 0.f, 0.f};
#pragma unroll
    for (int j = 0; j < 4; ++j) {
        int idx = tid + j * 256;
        int r = idx >> 3, q8 = (idx & 7) * 8;
        *(s16x8*)&Pt[r * 72 + q8] = *(const s16x8*)&Pg[(long)r * 64 + q8];
    }
#pragma unroll
    for (int j = 0; j < 2; ++j) {
        int idx = tid + j * 256;
        int r = idx >> 3, q8 = (idx & 7) * 8;
        *(s16x8*)&Qt[r * 72 + q8] = *(const s16x8*)&AcT[(long)r * 64 + q8];
    }
    __syncthreads();
#pragma unroll
    for (int ks = 0; ks < 2; ++ks) {
        s16x8 pa[2], qb[4];
#pragma unroll
        for (int i = 0; i < 2; ++i) pa[i] = *(const s16x8*)&Pt[(mq + 16 * i + fr) * 72 + ks * 32 + qd * 8];
#pragma unroll
        for (int j = 0; j < 4; ++j) qb[j] = *(const s16x8*)&Qt[(16 * j + fr) * 72 + ks * 32 + qd * 8];
#pragma unroll
        for (int i = 0; i < 2; ++i)
#pragma unroll
            for (int j = 0; j < 4; ++j) acc[i][j] = MFMA(pa[i], qb[j], acc[i][j]);
    }
#pragma unroll
    for (int i = 0; i < 2; ++i)
#pragma unroll
        for (int j = 0; j < 4; ++j) {
            int Rb = m0 + mq + 16 * i + qd * 4;
            int xo = Rb >> 7, o = Rb & 127;
            int yo = 16 * j + fr;
            ushort4 pk;
            const float* bg = b1 + br * 128 + o;
            pk.x = bfr(fmaxf(acc[i][j][0] + bg[0], 0.f));
            pk.y = bfr(fmaxf(acc[i][j][1] + bg[1], 0.f));
            pk.z = bfr(fmaxf(acc[i][j][2] + bg[2], 0.f));
            pk.w = bfr(fmaxf(acc[i][j][3] + bg[3], 0.f));
            *(ushort4*)&h1[(long)z2 * 524288 + ((long)yo * 64 + xo) * 128 + o] = pk;
        }
}

// ---------------- conv2: implicit GEMM ----------------
__global__ __launch_bounds__(256, 2) void k_conv2(const u16* __restrict__ h1, const u16* __restrict__ W2a,
                                                  const float* __restrict__ b2, u16* __restrict__ h2) {
    __shared__ __align__(16) short Pt[128 * 40];
    __shared__ __align__(16) short Qt[128 * 40];
    const int b = blockIdx.z, br = blockIdx.y, y0 = blockIdx.x * 2;
    const int z2 = br * 8 + b;
    const int tid = threadIdx.x;
    const int lane = tid & 63, wave = tid >> 6;
    const int fr = lane & 15, qd = lane >> 4;
    const int mq = (wave >> 1) * 64, nq = (wave & 1) * 64;
    f32x4 acc[4][4];
#pragma unroll
    for (int i = 0; i < 4; ++i)
#pragma unroll
        for (int j = 0; j < 4; ++j) acc[i][j] = (f32x4){0.f, 0.f, 0.f, 0.f};
    const u16* hb = h1 + (long)z2 * 524288;
    const u16* Qg = W2a + (long)br * 147456;
    for (int ch = 0; ch < 36; ++ch) {
        const int t9 = ch >> 2, ci0 = (ch & 3) * 32;
        const int ky = t9 / 3, kx = t9 - 3 * ky;
        const int dy = 2 * ky - 2, dx = 2 * kx - 2;
        __syncthreads();
#pragma unroll
        for (int j = 0; j < 2; ++j) {
            int idx = tid + j * 256;
            int r = idx >> 2, q4 = (idx & 3) * 8;
            int ry = r >> 6, x = r & 63;
            int ysrc = y0 + ry + dy, xsrc = x + dx;
            s16x8 v = {0, 0, 0, 0, 0, 0, 0, 0};
            if ((unsigned)ysrc < 64u && (unsigned)xsrc < 64u)
                v = *(const s16x8*)&hb[((long)ysrc * 64 + xsrc) * 128 + ci0 + q4];
            *(s16x8*)&Pt[r * 40 + q4] = v;
            *(s16x8*)&Qt[r * 40 + q4] = *(const s16x8*)&Qg[(long)r * 1152 + ch * 32 + q4];
        }
        __syncthreads();
        s16x8 pa[4], qb[4];
#pragma unroll
        for (int i = 0; i < 4; ++i) {
            pa[i] = *(const s16x8*)&Pt[(mq + 16 * i + fr) * 40 + qd * 8];
            qb[i] = *(const s16x8*)&Qt[(nq + 16 * i + fr) * 40 + qd * 8];
        }
#pragma unroll
        for (int i = 0; i < 4; ++i)
#pragma unroll
            for (int j = 0; j < 4; ++j) acc[i][j] = MFMA(pa[i], qb[j], acc[i][j]);
    }
#pragma unroll
    for (int i = 0; i < 4; ++i)
#pragma unroll
        for (int j = 0; j < 4; ++j) {
            int rowb = mq + 16 * i + qd * 4;
            int o = nq + 16 * j + fr;
            float bb = b2[br * 128 + o];
#pragma unroll
            for (int r = 0; r < 4; ++r) {
                float v = fmaxf(acc[i][j][r] + bb, 0.f);
                h2[(long)z2 * 524288 + ((long)y0 * 64 + rowb + r) * 128 + o] = bfr(v);
            }
        }
}

// ---------------- conv3 ----------------
__global__ __launch_bounds__(256, 2) void k_conv3(const u16* __restrict__ h2, const u16* __restrict__ W3b,
                                                  const float* __restrict__ b3, float* __restrict__ out) {
    __shared__ __align__(16) short Pt[128 * 40];
    __shared__ __align__(16) short Qt[128 * 40];
    const int b = blockIdx.z, br = blockIdx.y, p0 = blockIdx.x * 128;
    const int z2 = br * 8 + b;
    const int tid = threadIdx.x;
    const int lane = tid & 63, wave = tid >> 6;
    const int fr = lane & 15, qd = lane >> 4;
    const int mq = (wave >> 1) * 64, nq = (wave & 1) * 64;
    f32x4 acc[4][4];
#pragma unroll
    for (int i = 0; i < 4; ++i)
#pragma unroll
        for (int j = 0; j < 4; ++j) acc[i][j] = (f32x4){0.f, 0.f, 0.f, 0.f};
    const u16* Pg = h2 + (long)z2 * 524288 + (long)p0 * 128;
    const u16* Qg = W3b + (long)br * 16384;
    for (int ch = 0; ch < 4; ++ch) {
        const int k0 = ch * 32;
        __syncthreads();
#pragma unroll
        for (int j = 0; j < 2; ++j) {
            int idx = tid + j * 256;
            int r = idx >> 2, q4 = (idx & 3) * 8;
            *(s16x8*)&Pt[r * 40 + q4] = *(const s16x8*)&Pg[(long)r * 128 + k0 + q4];
            *(s16x8*)&Qt[r * 40 + q4] = *(const s16x8*)&Qg[(long)r * 128 + k0 + q4];
        }
        __syncthreads();
        s16x8 pa[4], qb[4];
#pragma unroll
        for (int i = 0; i < 4; ++i) {
            pa[i] = *(const s16x8*)&Pt[(mq + 16 * i + fr) * 40 + qd * 8];
            qb[i] = *(const s16x8*)&Qt[(nq + 16 * i + fr) * 40 + qd * 8];
        }
#pragma unroll
        for (int i = 0; i < 4; ++i)
#pragma unroll
            for (int j = 0; j < 4; ++j) acc[i][j] = MFMA(pa[i], qb[j], acc[i][j]);
    }
#pragma unroll
    for (int i = 0; i < 4; ++i)
#pragma unroll
        for (int j = 0; j < 4; ++j) {
            int rowb = mq + 16 * i + qd * 4;
            int o = nq + 16 * j + fr;
            float bb = b3[br * 128 + o];
            float4 v = make_float4(fmaxf(acc[i][j][0] + bb, 0.f), fmaxf(acc[i][j][1] + bb, 0.f),
                                   fmaxf(acc[i][j][2] + bb, 0.f), fmaxf(acc[i][j][3] + bb, 0.f));
            *(float4*)&out[((long)b * 512 + br * 128 + o) * 4096 + p0 + rowb] = v;
        }
}

// ---------------- softmax gating + residual ----------------
__global__ __launch_bounds__(256) void k_final(const float* __restrict__ x, float* __restrict__ io) {
    const int bm = blockIdx.x;
    const int b = bm >> 6, m = bm & 63;
    const int n = threadIdx.x & 63, grp = threadIdx.x >> 6;
    const long base = ((long)b * 512) * 4096 + m * 64 + n;
    __shared__ float red[4][64];
    float mx = -1e30f;
    for (int c = grp * 128; c < grp * 128 + 128; ++c)
        mx = fmaxf(mx, io[base + (long)c * 4096]);
    red[grp][n] = mx;
    __syncthreads();
    const float M = fmaxf(fmaxf(red[0][n], red[1][n]), fmaxf(red[2][n], red[3][n]));
    __syncthreads();
    float s = 0.f;
    for (int c = grp * 128; c < grp * 128 + 128; ++c)
        s += __expf(io[base + (long)c * 4096] - M);
    red[grp][n] = s;
    __syncthreads();
    const float S = red[0][n] + red[1][n] + red[2][n] + red[3][n];
    const float inv = 1.0f / S;
    for (int c = grp * 128; c < grp * 128 + 128; ++c) {
        long a = base + (long)c * 4096;
        float w = __expf(io[a] - M) * inv;
        float xv = x[a];
        io[a] = xv * w + xv;
    }
}

// ---------------------------------------------------------------------------
extern "C" void kernel_launch(void* const* d_in, const int* in_sizes, int n_in,
                              void* d_out, int out_size, void* d_ws, size_t ws_size,
                              hipStream_t stream) {
    (void)in_sizes; (void)n_in; (void)out_size; (void)ws_size;
    const float* x  = (const float*)d_in[0];
    const float* W1 = (const float*)d_in[1];
    const float* b1 = (const float*)d_in[2];
    const float* W2 = (const float*)d_in[3];
    const float* b2 = (const float*)d_in[4];
    const float* W3 = (const float*)d_in[5];
    const float* b3 = (const float*)d_in[6];
    float* out = (float*)d_out;
    float* ws = (float*)d_ws;

    float* t    = ws + OFF_T;
    unsigned* h19 = (unsigned*)(ws + OFF_H19);
    u16*   h1pre= (u16*)(ws + OFF_H1P);
    u16*   X2   = (u16*)(ws + OFF_X2);
    u16*   thi  = (u16*)(ws + OFF_THI);
    u16*   tlo  = (u16*)(ws + OFF_TLO);
    u16*   h1   = (u16*)(ws + OFF_H1);
    float* D    = ws + OFF_D;
    u16*   h2   = (u16*)(ws + OFF_H2);
    float* Ak   = ws + OFF_AK;
    u16*   Akh  = (u16*)(ws + OFF_AKH);
    u16*   Akl  = (u16*)(ws + OFF_AKL);
    u16*   AcT  = (u16*)(ws + OFF_ACT);
    u16*   Gb   = (u16*)(ws + OFF_GBF);
    u16*   W2a  = (u16*)(ws + OFF_W2A);
    u16*   W3b  = (u16*)(ws + OFF_W3B);
    unsigned* hist1 = (unsigned*)(ws + OFF_HIST);
    unsigned* sel   = (unsigned*)(ws + OFF_SEL);
    float* thr      = ws + OFF_THR;
    float* Ac       = ws + OFF_AC;

    k_build_mats<<<1024, 256, 0, stream>>>(Ak, Akh, Akl, AcT, Ac);
    k_zero<<<16, 256, 0, stream>>>(hist1, 4096);
    k_G_bf<<<1024, 256, 0, stream>>>(W1, Ak, Gb);
    k_wprep<<<2304, 256, 0, stream>>>(W2, W3, W2a, W3b);

    // forward spatial DCT (fp32) -> t NCHW
    k_tile_fwd<<<4096, 256, 0, stream>>>(x, t, Ac);
    // transpose + split to NHWC bf16
    k_tsplit<<<dim3(64, 8, 8), 256, 0, stream>>>(t, thi, tlo);
    // t is now consumed -> region A reusable: zero the 19-bit histogram
    k_zero19<<<2048, 256, 0, stream>>>((uint4*)h19);
    // C-axis DCT via split-bf16 MFMA -> D fp32 NHWC (+ fused hist1)
    k_cgemm<<<dim3(4, 32, 8), 256, 0, stream>>>(thi, tlo, Akh, Akl, D, hist1);

    // exact top-k thresholds: 12-bit prefix (fused) + single 19-bit resolve pass
    k_scan1<<<1, 256, 0, stream>>>(hist1, sel);
    k_hist19<<<2048, 256, 0, stream>>>((const float4*)D, sel, h19);
    k_scan19<<<4, 1024, 0, stream>>>(h19, sel, thr);

    // branches (all 4 concurrent via grid.y)
    k_conv1<<<dim3(32, 4, 8), 256, 0, stream>>>(D, Gb, thr, h1pre);
    k_idct1<<<dim3(64, 4, 8), 256, 0, stream>>>(h1pre, AcT, X2);
    k_idct2<<<dim3(64, 4, 8), 256, 0, stream>>>(X2, AcT, b1, h1);
    k_conv2<<<dim3(32, 4, 8), 256, 0, stream>>>(h1, W2a, b2, h2);
    k_conv3<<<dim3(32, 4, 8), 256, 0, stream>>>(h2, W3b, b3, out);

    k_final<<<512, 256, 0, stream>>>(x, out);
}

// Round 5
// 805.880 us; speedup vs baseline: 82.8199x; 82.8199x over previous
//
#include <hip/hip_runtime.h>
#include <math.h>

#define NB   8
#define NC   512
#define SP   4096
#define TOT  16777216L
static const double PI_D = 3.14159265358979323846;

typedef short s16x8 __attribute__((ext_vector_type(8)));
typedef float f32x4 __attribute__((ext_vector_type(4)));
typedef unsigned short u16;

// ---------------- ws layout (float units) ----------------
// region A [0,16777216): t fp32; then selection partials; then h1pre+X2 bf16
// region B [16777216,25165824): thi/tlo bf16; later h1 bf16
// region C [25165824,41943040): D fp32; later h2 bf16 in first half
#define OFF_T    0L
#define OFF_PA   0L                   // partial hist2: 512 x 4096 u32
#define OFF_PB   2097152L             // partial hist3: 512 x 2048 u32
#define OFF_H2R  3145728L             // reduced hist2: 4096 u32
#define OFF_H3R  3149824L             // reduced hist3: 2048 u32
#define OFF_H1P  0L
#define OFF_X2   8388608L
#define OFF_THI  16777216L
#define OFF_TLO  20971520L
#define OFF_H1   16777216L
#define OFF_D    25165824L
#define OFF_H2   25165824L
#define OFF_AK   41943040L
#define OFF_AKH  42205184L
#define OFF_AKL  42336256L
#define OFF_ACT  42467328L
#define OFF_GBF  42468352L
#define OFF_W2A  42599424L
#define OFF_W3B  42894336L
#define OFF_HIST 42927104L            // hist1 4096 (u32)
#define OFF_SEL  42937344L            // u32[16]
#define OFF_THR  42937360L            // float[4]
#define OFF_AC   42937368L

__device__ inline u16 bfr(float x) {
    unsigned u = __float_as_uint(x);
    unsigned r = u + 0x7fffu + ((u >> 16) & 1u);
    return (u16)(r >> 16);
}
__device__ inline float bff(u16 h) { return __uint_as_float(((unsigned)h) << 16); }

#define MFMA(a, b, c) __builtin_amdgcn_mfma_f32_16x16x32_bf16((a), (b), (c), 0, 0, 0)

// ---------------- setup kernels ----------------
__global__ void k_build_mats(float* __restrict__ Ak, u16* __restrict__ Akh, u16* __restrict__ Akl,
                             u16* __restrict__ AcT, float* __restrict__ Ac) {
    int idx = blockIdx.x * 256 + threadIdx.x;
    if (idx < 512 * 512) {
        int i = idx >> 9, j = idx & 511;
        double v = cos((double)i * ((double)j + 0.5) * (PI_D / 512.0)) * sqrt(2.0 / 512.0);
        if (i == 0) v *= (1.0 / sqrt(2.0));
        float f = (float)v;
        Ak[idx] = f;
        u16 h = bfr(f);
        Akh[idx] = h;
        Akl[idx] = bfr(f - bff(h));
    }
    if (idx < 64 * 64) {
        int i = idx >> 6, j = idx & 63;
        double v = cos((double)i * ((double)j + 0.5) * (PI_D / 64.0)) * sqrt(2.0 / 64.0);
        if (i == 0) v *= (1.0 / sqrt(2.0));
        Ac[idx] = (float)v;
        int n = idx >> 6, np = idx & 63;
        double w = cos((double)np * ((double)n + 0.5) * (PI_D / 64.0)) * sqrt(2.0 / 64.0);
        if (np == 0) w *= (1.0 / sqrt(2.0));
        AcT[idx] = bfr((float)w);
    }
}

__global__ void k_zero(unsigned* __restrict__ p, int n) {
    int i = blockIdx.x * 256 + threadIdx.x;
    if (i < n) p[i] = 0u;
}

// G_bf[i][o][kc] = bf16( sum_c W1[i][o][c] * Ak[kc][c] )
__global__ void k_G_bf(const float* __restrict__ W1, const float* __restrict__ Ak,
                       u16* __restrict__ G) {
    int idx = blockIdx.x * 256 + threadIdx.x;
    int kc = idx & 511, oi = idx >> 9;
    const float* w = W1 + (long)oi * 512;
    const float* a = Ak + (long)kc * 512;
    float s = 0.f;
    for (int c = 0; c < 512; ++c) s += w[c] * a[c];
    G[idx] = bfr(s);
}

// W2a[i][o][t*128+ci] = W2[i][o][ci][t];  W3b = cvt(W3)
__global__ void k_wprep(const float* __restrict__ W2, const float* __restrict__ W3,
                        u16* __restrict__ W2a, u16* __restrict__ W3b) {
    int idx = blockIdx.x * 256 + threadIdx.x;
    if (idx < 4 * 128 * 1152) {
        int k = idx % 1152;
        int oi = idx / 1152;
        int t = k >> 7, ci = k & 127;
        W2a[idx] = bfr(W2[((long)oi * 128 + ci) * 9 + t]);
    }
    if (idx < 65536) W3b[idx] = bfr(W3[idx]);
}

// ---------------- forward 2D DCT tile (fp32) ----------------
__global__ __launch_bounds__(256) void k_tile_fwd(const float* __restrict__ in,
                                                  float* __restrict__ out,
                                                  const float* __restrict__ A64) {
    __shared__ __align__(16) float Ms[64][68];
    __shared__ __align__(16) float Ts[64][68];
    __shared__ __align__(16) float Ss[64][68];
    const int tid = threadIdx.x;
    const long tile = blockIdx.x;
    const float* __restrict__ src = in + tile * 4096;
    float* __restrict__ dst = out + tile * 4096;
    for (int idx = tid; idx < 4096; idx += 256) {
        int r = idx >> 6, c = idx & 63;
        Ms[c][r] = A64[idx];
        Ts[r][c] = src[idx];
    }
    __syncthreads();
    const int tx = tid & 15, ty = tid >> 4;
    float acc[4][4];
#pragma unroll
    for (int i = 0; i < 4; ++i)
#pragma unroll
        for (int j = 0; j < 4; ++j) acc[i][j] = 0.f;
#pragma unroll 4
    for (int j = 0; j < 64; ++j) {
        float4 bv = *(const float4*)&Ms[j][tx * 4];
        float a0 = Ts[ty * 4 + 0][j], a1 = Ts[ty * 4 + 1][j];
        float a2 = Ts[ty * 4 + 2][j], a3 = Ts[ty * 4 + 3][j];
        acc[0][0] += a0 * bv.x; acc[0][1] += a0 * bv.y; acc[0][2] += a0 * bv.z; acc[0][3] += a0 * bv.w;
        acc[1][0] += a1 * bv.x; acc[1][1] += a1 * bv.y; acc[1][2] += a1 * bv.z; acc[1][3] += a1 * bv.w;
        acc[2][0] += a2 * bv.x; acc[2][1] += a2 * bv.y; acc[2][2] += a2 * bv.z; acc[2][3] += a2 * bv.w;
        acc[3][0] += a3 * bv.x; acc[3][1] += a3 * bv.y; acc[3][2] += a3 * bv.z; acc[3][3] += a3 * bv.w;
    }
#pragma unroll
    for (int i = 0; i < 4; ++i)
        *(float4*)&Ss[ty * 4 + i][tx * 4] = make_float4(acc[i][0], acc[i][1], acc[i][2], acc[i][3]);
    __syncthreads();
#pragma unroll
    for (int i = 0; i < 4; ++i)
#pragma unroll
        for (int j = 0; j < 4; ++j) acc[i][j] = 0.f;
#pragma unroll 4
    for (int j = 0; j < 64; ++j) {
        float4 av = *(const float4*)&Ms[j][ty * 4];
        float4 sv = *(const float4*)&Ss[j][tx * 4];
        acc[0][0] += av.x * sv.x; acc[0][1] += av.x * sv.y; acc[0][2] += av.x * sv.z; acc[0][3] += av.x * sv.w;
        acc[1][0] += av.y * sv.x; acc[1][1] += av.y * sv.y; acc[1][2] += av.y * sv.z; acc[1][3] += av.y * sv.w;
        acc[2][0] += av.z * sv.x; acc[2][1] += av.z * sv.y; acc[2][2] += av.z * sv.z; acc[2][3] += av.z * sv.w;
        acc[3][0] += av.w * sv.x; acc[3][1] += av.w * sv.y; acc[3][2] += av.w * sv.z; acc[3][3] += av.w * sv.w;
    }
#pragma unroll
    for (int i = 0; i < 4; ++i)
        *(float4*)&dst[(ty * 4 + i) * 64 + tx * 4] = make_float4(acc[i][0], acc[i][1], acc[i][2], acc[i][3]);
}

// ---------------- transpose + split: t NCHW fp32 -> thi/tlo NHWC bf16 ----------------
__global__ __launch_bounds__(256) void k_tsplit(const float* __restrict__ t,
                                                u16* __restrict__ thi, u16* __restrict__ tlo) {
    __shared__ float Ls[64][65];
    const int b = blockIdx.z, cg = blockIdx.y, pg = blockIdx.x;
    const int tid = threadIdx.x;
    const float* src = t + ((long)b * 512 + cg * 64) * 4096 + pg * 64;
#pragma unroll
    for (int j = 0; j < 4; ++j) {
        int c = (tid >> 4) + j * 16, p4 = (tid & 15) * 4;
        float4 v = *(const float4*)&src[(long)c * 4096 + p4];
        Ls[c][p4 + 0] = v.x; Ls[c][p4 + 1] = v.y; Ls[c][p4 + 2] = v.z; Ls[c][p4 + 3] = v.w;
    }
    __syncthreads();
#pragma unroll
    for (int j = 0; j < 2; ++j) {
        int idx = tid + j * 256;
        int p = idx >> 3, c8 = idx & 7;
        s16x8 vh, vl;
#pragma unroll
        for (int q = 0; q < 8; ++q) {
            float f = Ls[c8 * 8 + q][p];
            u16 h = bfr(f);
            vh[q] = (short)h;
            vl[q] = (short)bfr(f - bff(h));
        }
        long addr = ((long)b * 4096 + pg * 64 + p) * 512 + cg * 64 + c8 * 8;
        *(s16x8*)&thi[addr] = vh;
        *(s16x8*)&tlo[addr] = vl;
    }
}

// ---------------- C-DCT GEMM + fused hist1 ----------------
__global__ __launch_bounds__(256, 2) void k_cgemm(const u16* __restrict__ thi, const u16* __restrict__ tlo,
                                                  const u16* __restrict__ Akh, const u16* __restrict__ Akl,
                                                  float* __restrict__ D, unsigned* __restrict__ g1) {
    __shared__ __align__(16) short Ph[128 * 40];
    __shared__ __align__(16) short Pl[128 * 40];
    __shared__ __align__(16) short Qh[128 * 40];
    __shared__ __align__(16) short Ql[128 * 40];
    __shared__ unsigned hh[4096];
    const int b = blockIdx.z;
    const int p0 = blockIdx.y * 128, kc0 = blockIdx.x * 128;
    const int tid = threadIdx.x;
    const int lane = tid & 63, wave = tid >> 6;
    const int fr = lane & 15, qd = lane >> 4;
    const int mq = (wave >> 1) * 64, nq = (wave & 1) * 64;
    for (int t = tid; t < 4096; t += 256) hh[t] = 0u;
    f32x4 acc[4][4];
#pragma unroll
    for (int i = 0; i < 4; ++i)
#pragma unroll
        for (int j = 0; j < 4; ++j) acc[i][j] = (f32x4){0.f, 0.f, 0.f, 0.f};
    const u16* Pgh = thi + ((long)b * 4096 + p0) * 512;
    const u16* Pgl = tlo + ((long)b * 4096 + p0) * 512;
    const u16* Qgh = Akh + (long)kc0 * 512;
    const u16* Qgl = Akl + (long)kc0 * 512;
    for (int ch = 0; ch < 16; ++ch) {
        const int k0 = ch * 32;
        __syncthreads();
#pragma unroll
        for (int j = 0; j < 2; ++j) {
            int idx = tid + j * 256;
            int r = idx >> 2, q4 = (idx & 3) * 8;
            *(s16x8*)&Ph[r * 40 + q4] = *(const s16x8*)&Pgh[(long)r * 512 + k0 + q4];
            *(s16x8*)&Pl[r * 40 + q4] = *(const s16x8*)&Pgl[(long)r * 512 + k0 + q4];
            *(s16x8*)&Qh[r * 40 + q4] = *(const s16x8*)&Qgh[(long)r * 512 + k0 + q4];
            *(s16x8*)&Ql[r * 40 + q4] = *(const s16x8*)&Qgl[(long)r * 512 + k0 + q4];
        }
        __syncthreads();
        s16x8 ph[4], pl[4], qh[4], ql[4];
#pragma unroll
        for (int i = 0; i < 4; ++i) {
            ph[i] = *(const s16x8*)&Ph[(mq + 16 * i + fr) * 40 + qd * 8];
            pl[i] = *(const s16x8*)&Pl[(mq + 16 * i + fr) * 40 + qd * 8];
            qh[i] = *(const s16x8*)&Qh[(nq + 16 * i + fr) * 40 + qd * 8];
            ql[i] = *(const s16x8*)&Ql[(nq + 16 * i + fr) * 40 + qd * 8];
        }
#pragma unroll
        for (int i = 0; i < 4; ++i)
#pragma unroll
            for (int j = 0; j < 4; ++j) {
                acc[i][j] = MFMA(ph[i], qh[j], acc[i][j]);
                acc[i][j] = MFMA(ph[i], ql[j], acc[i][j]);
                acc[i][j] = MFMA(pl[i], qh[j], acc[i][j]);
            }
    }
#pragma unroll
    for (int i = 0; i < 4; ++i)
#pragma unroll
        for (int j = 0; j < 4; ++j) {
            int rowb = mq + 16 * i + qd * 4;
            int col = kc0 + nq + 16 * j + fr;
#pragma unroll
            for (int r = 0; r < 4; ++r) {
                float v = acc[i][j][r];
                D[((long)b * 4096 + p0 + rowb + r) * 512 + col] = v;
                atomicAdd(&hh[__float_as_uint(fabsf(v)) >> 19], 1u);
            }
        }
    __syncthreads();
    for (int t = tid; t < 4096; t += 256) {
        unsigned c = hh[t];
        if (c) atomicAdd(&g1[t], c);
    }
}

// ---------------- selection ----------------
__global__ void k_scan1(const unsigned* __restrict__ hist, unsigned* __restrict__ sel) {
    __shared__ unsigned chunk[256];
    __shared__ unsigned above[256];
    const int t = threadIdx.x;
    unsigned s = 0;
#pragma unroll
    for (int j = 0; j < 16; ++j) s += hist[t * 16 + j];
    chunk[t] = s;
    __syncthreads();
    if (t == 0) {
        unsigned a = 0;
        for (int c = 255; c >= 0; --c) { above[c] = a; a += chunk[c]; }
    }
    __syncthreads();
    const unsigned kv[4] = {4194304u, 1048576u, 262144u, 65536u};
    unsigned run = above[t];
    for (int j = 15; j >= 0; --j) {
        unsigned bin = t * 16 + j;
        unsigned hb = hist[bin];
        unsigned Sab = run;
        run += hb;
#pragma unroll
        for (int i = 0; i < 4; ++i)
            if (run >= kv[i] && Sab < kv[i]) { sel[i] = bin; sel[4 + i] = kv[i] - Sab; }
    }
}

// level-2 pass: LDS histogram of next 10 bits for 4 selected prefixes; plain store
__global__ __launch_bounds__(256) void k_hist2p(const float4* __restrict__ D,
                                                const unsigned* __restrict__ sel,
                                                unsigned* __restrict__ partial) {
    __shared__ unsigned h[4096];
    for (int i = threadIdx.x; i < 4096; i += 256) h[i] = 0u;
    __syncthreads();
    const unsigned p0 = sel[0], p1 = sel[1], p2 = sel[2], p3 = sel[3];
    const long n4 = TOT / 4;
    for (long idx = (long)blockIdx.x * 256 + threadIdx.x; idx < n4; idx += (long)gridDim.x * 256) {
        float4 v = D[idx];
        float f[4] = {v.x, v.y, v.z, v.w};
#pragma unroll
        for (int q = 0; q < 4; ++q) {
            unsigned u = __float_as_uint(fabsf(f[q]));
            unsigned pre = u >> 19, mid = (u >> 9) & 1023u;
            if (pre == p0) atomicAdd(&h[mid], 1u);
            if (pre == p1) atomicAdd(&h[1024 + mid], 1u);
            if (pre == p2) atomicAdd(&h[2048 + mid], 1u);
            if (pre == p3) atomicAdd(&h[3072 + mid], 1u);
        }
    }
    __syncthreads();
    unsigned* dst = partial + (long)blockIdx.x * 4096;
    for (int i = threadIdx.x; i < 4096; i += 256) dst[i] = h[i];
}

// reduce partial[nrows][nbins] -> out[nbins] (no atomics, coalesced)
__global__ __launch_bounds__(256) void k_red(const unsigned* __restrict__ partial,
                                             unsigned* __restrict__ out, int nbins, int nrows) {
    int bin = blockIdx.x * 256 + threadIdx.x;
    if (bin >= nbins) return;
    unsigned s = 0;
#pragma unroll 16
    for (int r = 0; r < nrows; ++r) s += partial[(long)r * nbins + bin];
    out[bin] = s;
}

__global__ void k_scan2(const unsigned* __restrict__ hist2, unsigned* __restrict__ sel) {
    __shared__ unsigned chunk[256];
    __shared__ unsigned above[256];
    const int t = threadIdx.x;
    for (int i = 0; i < 4; ++i) {
        const unsigned* h = hist2 + i * 1024;
        unsigned r = sel[4 + i];
        unsigned s = h[t * 4] + h[t * 4 + 1] + h[t * 4 + 2] + h[t * 4 + 3];
        chunk[t] = s;
        __syncthreads();
        if (t == 0) {
            unsigned a = 0;
            for (int c = 255; c >= 0; --c) { above[c] = a; a += chunk[c]; }
        }
        __syncthreads();
        unsigned run = above[t];
        for (int j = 3; j >= 0; --j) {
            unsigned bin = t * 4 + j;
            unsigned hb = h[bin];
            unsigned Sab = run;
            run += hb;
            if (run >= r && Sab < r) { sel[8 + i] = bin; sel[12 + i] = r - Sab; }
        }
        __syncthreads();
    }
}

// level-3 pass: LDS histogram of last 9 bits for 4 selected 22-bit prefixes
__global__ __launch_bounds__(256) void k_hist3p(const float4* __restrict__ D,
                                                const unsigned* __restrict__ sel,
                                                unsigned* __restrict__ partial) {
    __shared__ unsigned h[2048];
    for (int i = threadIdx.x; i < 2048; i += 256) h[i] = 0u;
    __syncthreads();
    unsigned pre2[4];
#pragma unroll
    for (int i = 0; i < 4; ++i) pre2[i] = (sel[i] << 10) | sel[8 + i];
    const long n4 = TOT / 4;
    for (long idx = (long)blockIdx.x * 256 + threadIdx.x; idx < n4; idx += (long)gridDim.x * 256) {
        float4 v = D[idx];
        float f[4] = {v.x, v.y, v.z, v.w};
#pragma unroll
        for (int q = 0; q < 4; ++q) {
            unsigned u = __float_as_uint(fabsf(f[q]));
            unsigned p = u >> 9, low = u & 511u;
            if (p == pre2[0]) atomicAdd(&h[low], 1u);
            if (p == pre2[1]) atomicAdd(&h[512 + low], 1u);
            if (p == pre2[2]) atomicAdd(&h[1024 + low], 1u);
            if (p == pre2[3]) atomicAdd(&h[1536 + low], 1u);
        }
    }
    __syncthreads();
    unsigned* dst = partial + (long)blockIdx.x * 2048;
    for (int i = threadIdx.x; i < 2048; i += 256) dst[i] = h[i];
}

__global__ void k_scan3(const unsigned* __restrict__ hist3, const unsigned* __restrict__ sel,
                        float* __restrict__ thr) {
    __shared__ unsigned chunk[256];
    __shared__ unsigned above[256];
    const int t = threadIdx.x;
    for (int i = 0; i < 4; ++i) {
        const unsigned* h = hist3 + i * 512;
        unsigned r = sel[12 + i];
        unsigned s = h[t * 2] + h[t * 2 + 1];
        chunk[t] = s;
        __syncthreads();
        if (t == 0) {
            unsigned a = 0;
            for (int c = 255; c >= 0; --c) { above[c] = a; a += chunk[c]; }
        }
        __syncthreads();
        unsigned run = above[t];
        for (int j = 1; j >= 0; --j) {
            unsigned bin = t * 2 + j;
            unsigned hb = h[bin];
            unsigned Sab = run;
            run += hb;
            if (run >= r && Sab < r)
                thr[i] = __uint_as_float((sel[i] << 19) | (sel[8 + i] << 9) | bin);
        }
        __syncthreads();
    }
}

// ---------------- conv1 fused with IDCT_C ----------------
__global__ __launch_bounds__(256, 2) void k_conv1(const float* __restrict__ D, const u16* __restrict__ Gb,
                                                  const float* __restrict__ thrp, u16* __restrict__ h1pre) {
    __shared__ __align__(16) short Pt[128 * 40];
    __shared__ __align__(16) short Qt[128 * 40];
    const int b = blockIdx.z, br = blockIdx.y, p0 = blockIdx.x * 128;
    const int z2 = br * 8 + b;
    const float thr = thrp[br];
    const int tid = threadIdx.x;
    const int lane = tid & 63, wave = tid >> 6;
    const int fr = lane & 15, qd = lane >> 4;
    const int mq = (wave >> 1) * 64, nq = (wave & 1) * 64;
    f32x4 acc[4][4];
#pragma unroll
    for (int i = 0; i < 4; ++i)
#pragma unroll
        for (int j = 0; j < 4; ++j) acc[i][j] = (f32x4){0.f, 0.f, 0.f, 0.f};
    const float* Pg = D + ((long)b * 4096 + p0) * 512;
    const u16* Qg = Gb + (long)br * 65536;
    for (int ch = 0; ch < 16; ++ch) {
        const int k0 = ch * 32;
        __syncthreads();
#pragma unroll
        for (int j = 0; j < 2; ++j) {
            int idx = tid + j * 256;
            int r = idx >> 2, q4 = (idx & 3) * 8;
            const float* src = &Pg[(long)r * 512 + k0 + q4];
            float4 v0 = *(const float4*)src;
            float4 v1 = *(const float4*)(src + 4);
            s16x8 m;
            float f[8] = {v0.x, v0.y, v0.z, v0.w, v1.x, v1.y, v1.z, v1.w};
#pragma unroll
            for (int q = 0; q < 8; ++q) m[q] = (short)(fabsf(f[q]) >= thr ? bfr(f[q]) : (u16)0);
            *(s16x8*)&Pt[r * 40 + q4] = m;
            *(s16x8*)&Qt[r * 40 + q4] = *(const s16x8*)&Qg[(long)r * 512 + k0 + q4];
        }
        __syncthreads();
        s16x8 pa[4], qb[4];
#pragma unroll
        for (int i = 0; i < 4; ++i) {
            pa[i] = *(const s16x8*)&Pt[(mq + 16 * i + fr) * 40 + qd * 8];
            qb[i] = *(const s16x8*)&Qt[(nq + 16 * i + fr) * 40 + qd * 8];
        }
#pragma unroll
        for (int i = 0; i < 4; ++i)
#pragma unroll
            for (int j = 0; j < 4; ++j) acc[i][j] = MFMA(pa[i], qb[j], acc[i][j]);
    }
#pragma unroll
    for (int i = 0; i < 4; ++i)
#pragma unroll
        for (int j = 0; j < 4; ++j) {
            int rowb = p0 + mq + 16 * i + qd * 4;
            int o = nq + 16 * j + fr;
            ushort4 pk;
            pk.x = bfr(acc[i][j][0]); pk.y = bfr(acc[i][j][1]);
            pk.z = bfr(acc[i][j][2]); pk.w = bfr(acc[i][j][3]);
            *(ushort4*)&h1pre[((long)z2 * 128 + o) * 4096 + rowb] = pk;
        }
}

// ---------------- IDCT passes ----------------
__global__ __launch_bounds__(256, 2) void k_idct1(const u16* __restrict__ h1pre, const u16* __restrict__ AcT,
                                                  u16* __restrict__ X2) {
    __shared__ __align__(16) short Pt[128 * 72];
    __shared__ __align__(16) short Qt[64 * 72];
    const int b = blockIdx.z, br = blockIdx.y, m0 = blockIdx.x * 128;
    const int z2 = br * 8 + b;
    const int tid = threadIdx.x;
    const int lane = tid & 63, wave = tid >> 6;
    const int fr = lane & 15, qd = lane >> 4;
    const int mq = wave * 32;
    const u16* Pg = h1pre + (long)z2 * 524288 + (long)m0 * 64;
    f32x4 acc[2][4];
#pragma unroll
    for (int i = 0; i < 2; ++i)
#pragma unroll
        for (int j = 0; j < 4; ++j) acc[i][j] = (f32x4){0.f, 0.f, 0.f, 0.f};
#pragma unroll
    for (int j = 0; j < 4; ++j) {
        int idx = tid + j * 256;
        int r = idx >> 3, q8 = (idx & 7) * 8;
        *(s16x8*)&Pt[r * 72 + q8] = *(const s16x8*)&Pg[(long)r * 64 + q8];
    }
#pragma unroll
    for (int j = 0; j < 2; ++j) {
        int idx = tid + j * 256;
        int r = idx >> 3, q8 = (idx & 7) * 8;
        *(s16x8*)&Qt[r * 72 + q8] = *(const s16x8*)&AcT[(long)r * 64 + q8];
    }
    __syncthreads();
#pragma unroll
    for (int ks = 0; ks < 2; ++ks) {
        s16x8 pa[2], qb[4];
#pragma unroll
        for (int i = 0; i < 2; ++i) pa[i] = *(const s16x8*)&Pt[(mq + 16 * i + fr) * 72 + ks * 32 + qd * 8];
#pragma unroll
        for (int j = 0; j < 4; ++j) qb[j] = *(const s16x8*)&Qt[(16 * j + fr) * 72 + ks * 32 + qd * 8];
#pragma unroll
        for (int i = 0; i < 2; ++i)
#pragma unroll
            for (int j = 0; j < 4; ++j) acc[i][j] = MFMA(pa[i], qb[j], acc[i][j]);
    }
#pragma unroll
    for (int i = 0; i < 2; ++i)
#pragma unroll
        for (int j = 0; j < 4; ++j) {
            int Rb = m0 + mq + 16 * i + qd * 4;
            int o = Rb >> 6, y = Rb & 63;
            int xo = 16 * j + fr;
            ushort4 pk;
            pk.x = bfr(acc[i][j][0]); pk.y = bfr(acc[i][j][1]);
            pk.z = bfr(acc[i][j][2]); pk.w = bfr(acc[i][j][3]);
            *(ushort4*)&X2[(long)z2 * 524288 + ((long)xo * 128 + o) * 64 + y] = pk;
        }
}

__global__ __launch_bounds__(256, 2) void k_idct2(const u16* __restrict__ X2, const u16* __restrict__ AcT,
                                                  const float* __restrict__ b1, u16* __restrict__ h1) {
    __shared__ __align__(16) short Pt[128 * 72];
    __shared__ __align__(16) short Qt[64 * 72];
    const int b = blockIdx.z, br = blockIdx.y, m0 = blockIdx.x * 128;
    const int z2 = br * 8 + b;
    const int tid = threadIdx.x;
    const int lane = tid & 63, wave = tid >> 6;
    const int fr = lane & 15, qd = lane >> 4;
    const int mq = wave * 32;
    const u16* Pg = X2 + (long)z2 * 524288 + (long)m0 * 64;
    f32x4 acc[2][4];
#pragma unroll
    for (int i = 0; i < 2; ++i)
#pragma unroll
        for (int j = 0; j < 4; ++j) acc[i][j] = (f32x4){0.f, 0.f, 0.f, 0.f};
#pragma unroll
    for (int j = 0; j < 4; ++j) {
        int idx = tid + j * 256;
        int r = idx >> 3, q8 = (idx & 7) * 8;
        *(s16x8*)&Pt[r * 72 + q8] = *(const s16x8*)&Pg[(long)r * 64 + q8];
    }
#pragma unroll
    for (int j = 0; j < 2; ++j) {
        int idx = tid + j * 256;
        int r = idx >> 3, q8 = (idx & 7) * 8;
        *(s16x8*)&Qt[r * 72 + q8] = *(const s16x8*)&AcT[(long)r * 64 + q8];
    }
    __syncthreads();
#pragma unroll
    for (int ks = 0; ks < 2; ++ks) {
        s16x8 pa[2], qb[4];
#pragma unroll
        for (int i = 0; i < 2; ++i) pa[i] = *(const s16x8*)&Pt[(mq + 16 * i + fr) * 72 + ks * 32 + qd * 8];
#pragma unroll
        for (int j = 0; j < 4; ++j) qb[j] = *(const s16x8*)&Qt[(16 * j + fr) * 72 + ks * 32 + qd * 8];
#pragma unroll
        for (int i = 0; i < 2; ++i)
#pragma unroll
            for (int j = 0; j < 4; ++j) acc[i][j] = MFMA(pa[i], qb[j], acc[i][j]);
    }
#pragma unroll
    for (int i = 0; i < 2; ++i)
#pragma unroll
        for (int j = 0; j < 4; ++j) {
            int Rb = m0 + mq + 16 * i + qd * 4;
            int xo = Rb >> 7, o = Rb & 127;
            int yo = 16 * j + fr;
            ushort4 pk;
            const float* bg = b1 + br * 128 + o;
            pk.x = bfr(fmaxf(acc[i][j][0] + bg[0], 0.f));
            pk.y = bfr(fmaxf(acc[i][j][1] + bg[1], 0.f));
            pk.z = bfr(fmaxf(acc[i][j][2] + bg[2], 0.f));
            pk.w = bfr(fmaxf(acc[i][j][3] + bg[3], 0.f));
            *(ushort4*)&h1[(long)z2 * 524288 + ((long)yo * 64 + xo) * 128 + o] = pk;
        }
}

// ---------------- conv2: implicit GEMM ----------------
__global__ __launch_bounds__(256, 2) void k_conv2(const u16* __restrict__ h1, const u16* __restrict__ W2a,
                                                  const float* __restrict__ b2, u16* __restrict__ h2) {
    __shared__ __align__(16) short Pt[128 * 40];
    __shared__ __align__(16) short Qt[128 * 40];
    const int b = blockIdx.z, br = blockIdx.y, y0 = blockIdx.x * 2;
    const int z2 = br * 8 + b;
    const int tid = threadIdx.x;
    const int lane = tid & 63, wave = tid >> 6;
    const int fr = lane & 15, qd = lane >> 4;
    const int mq = (wave >> 1) * 64, nq = (wave & 1) * 64;
    f32x4 acc[4][4];
#pragma unroll
    for (int i = 0; i < 4; ++i)
#pragma unroll
        for (int j = 0; j < 4; ++j) acc[i][j] = (f32x4){0.f, 0.f, 0.f, 0.f};
    const u16* hb = h1 + (long)z2 * 524288;
    const u16* Qg = W2a + (long)br * 147456;
    for (int ch = 0; ch < 36; ++ch) {
        const int t9 = ch >> 2, ci0 = (ch & 3) * 32;
        const int ky = t9 / 3, kx = t9 - 3 * ky;
        const int dy = 2 * ky - 2, dx = 2 * kx - 2;
        __syncthreads();
#pragma unroll
        for (int j = 0; j < 2; ++j) {
            int idx = tid + j * 256;
            int r = idx >> 2, q4 = (idx & 3) * 8;
            int ry = r >> 6, x = r & 63;
            int ysrc = y0 + ry + dy, xsrc = x + dx;
            s16x8 v = {0, 0, 0, 0, 0, 0, 0, 0};
            if ((unsigned)ysrc < 64u && (unsigned)xsrc < 64u)
                v = *(const s16x8*)&hb[((long)ysrc * 64 + xsrc) * 128 + ci0 + q4];
            *(s16x8*)&Pt[r * 40 + q4] = v;
            *(s16x8*)&Qt[r * 40 + q4] = *(const s16x8*)&Qg[(long)r * 1152 + ch * 32 + q4];
        }
        __syncthreads();
        s16x8 pa[4], qb[4];
#pragma unroll
        for (int i = 0; i < 4; ++i) {
            pa[i] = *(const s16x8*)&Pt[(mq + 16 * i + fr) * 40 + qd * 8];
            qb[i] = *(const s16x8*)&Qt[(nq + 16 * i + fr) * 40 + qd * 8];
        }
#pragma unroll
        for (int i = 0; i < 4; ++i)
#pragma unroll
            for (int j = 0; j < 4; ++j) acc[i][j] = MFMA(pa[i], qb[j], acc[i][j]);
    }
#pragma unroll
    for (int i = 0; i < 4; ++i)
#pragma unroll
        for (int j = 0; j < 4; ++j) {
            int rowb = mq + 16 * i + qd * 4;
            int o = nq + 16 * j + fr;
            float bb = b2[br * 128 + o];
#pragma unroll
            for (int r = 0; r < 4; ++r) {
                float v = fmaxf(acc[i][j][r] + bb, 0.f);
                h2[(long)z2 * 524288 + ((long)y0 * 64 + rowb + r) * 128 + o] = bfr(v);
            }
        }
}

// ---------------- conv3 ----------------
__global__ __launch_bounds__(256, 2) void k_conv3(const u16* __restrict__ h2, const u16* __restrict__ W3b,
                                                  const float* __restrict__ b3, float* __restrict__ out) {
    __shared__ __align__(16) short Pt[128 * 40];
    __shared__ __align__(16) short Qt[128 * 40];
    const int b = blockIdx.z, br = blockIdx.y, p0 = blockIdx.x * 128;
    const int z2 = br * 8 + b;
    const int tid = threadIdx.x;
    const int lane = tid & 63, wave = tid >> 6;
    const int fr = lane & 15, qd = lane >> 4;
    const int mq = (wave >> 1) * 64, nq = (wave & 1) * 64;
    f32x4 acc[4][4];
#pragma unroll
    for (int i = 0; i < 4; ++i)
#pragma unroll
        for (int j = 0; j < 4; ++j) acc[i][j] = (f32x4){0.f, 0.f, 0.f, 0.f};
    const u16* Pg = h2 + (long)z2 * 524288 + (long)p0 * 128;
    const u16* Qg = W3b + (long)br * 16384;
    for (int ch = 0; ch < 4; ++ch) {
        const int k0 = ch * 32;
        __syncthreads();
#pragma unroll
        for (int j = 0; j < 2; ++j) {
            int idx = tid + j * 256;
            int r = idx >> 2, q4 = (idx & 3) * 8;
            *(s16x8*)&Pt[r * 40 + q4] = *(const s16x8*)&Pg[(long)r * 128 + k0 + q4];
            *(s16x8*)&Qt[r * 40 + q4] = *(const s16x8*)&Qg[(long)r * 128 + k0 + q4];
        }
        __syncthreads();
        s16x8 pa[4], qb[4];
#pragma unroll
        for (int i = 0; i < 4; ++i) {
            pa[i] = *(const s16x8*)&Pt[(mq + 16 * i + fr) * 40 + qd * 8];
            qb[i] = *(const s16x8*)&Qt[(nq + 16 * i + fr) * 40 + qd * 8];
        }
#pragma unroll
        for (int i = 0; i < 4; ++i)
#pragma unroll
            for (int j = 0; j < 4; ++j) acc[i][j] = MFMA(pa[i], qb[j], acc[i][j]);
    }
#pragma unroll
    for (int i = 0; i < 4; ++i)
#pragma unroll
        for (int j = 0; j < 4; ++j) {
            int rowb = mq + 16 * i + qd * 4;
            int o = nq + 16 * j + fr;
            float bb = b3[br * 128 + o];
            float4 v = make_float4(fmaxf(acc[i][j][0] + bb, 0.f), fmaxf(acc[i][j][1] + bb, 0.f),
                                   fmaxf(acc[i][j][2] + bb, 0.f), fmaxf(acc[i][j][3] + bb, 0.f));
            *(float4*)&out[((long)b * 512 + br * 128 + o) * 4096 + p0 + rowb] = v;
        }
}

// ---------------- softmax gating + residual ----------------
__global__ __launch_bounds__(256) void k_final(const float* __restrict__ x, float* __restrict__ io) {
    const int bm = blockIdx.x;
    const int b = bm >> 6, m = bm & 63;
    const int n = threadIdx.x & 63, grp = threadIdx.x >> 6;
    const long base = ((long)b * 512) * 4096 + m * 64 + n;
    __shared__ float red[4][64];
    float mx = -1e30f;
    for (int c = grp * 128; c < grp * 128 + 128; ++c)
        mx = fmaxf(mx, io[base + (long)c * 4096]);
    red[grp][n] = mx;
    __syncthreads();
    const float M = fmaxf(fmaxf(red[0][n], red[1][n]), fmaxf(red[2][n], red[3][n]));
    __syncthreads();
    float s = 0.f;
    for (int c = grp * 128; c < grp * 128 + 128; ++c)
        s += __expf(io[base + (long)c * 4096] - M);
    red[grp][n] = s;
    __syncthreads();
    const float S = red[0][n] + red[1][n] + red[2][n] + red[3][n];
    const float inv = 1.0f / S;
    for (int c = grp * 128; c < grp * 128 + 128; ++c) {
        long a = base + (long)c * 4096;
        float w = __expf(io[a] - M) * inv;
        float xv = x[a];
        io[a] = xv * w + xv;
    }
}

// ---------------------------------------------------------------------------
extern "C" void kernel_launch(void* const* d_in, const int* in_sizes, int n_in,
                              void* d_out, int out_size, void* d_ws, size_t ws_size,
                              hipStream_t stream) {
    (void)in_sizes; (void)n_in; (void)out_size; (void)ws_size;
    const float* x  = (const float*)d_in[0];
    const float* W1 = (const float*)d_in[1];
    const float* b1 = (const float*)d_in[2];
    const float* W2 = (const float*)d_in[3];
    const float* b2 = (const float*)d_in[4];
    const float* W3 = (const float*)d_in[5];
    const float* b3 = (const float*)d_in[6];
    float* out = (float*)d_out;
    float* ws = (float*)d_ws;

    float* t    = ws + OFF_T;
    unsigned* pA  = (unsigned*)(ws + OFF_PA);
    unsigned* pB  = (unsigned*)(ws + OFF_PB);
    unsigned* h2r = (unsigned*)(ws + OFF_H2R);
    unsigned* h3r = (unsigned*)(ws + OFF_H3R);
    u16*   h1pre= (u16*)(ws + OFF_H1P);
    u16*   X2   = (u16*)(ws + OFF_X2);
    u16*   thi  = (u16*)(ws + OFF_THI);
    u16*   tlo  = (u16*)(ws + OFF_TLO);
    u16*   h1   = (u16*)(ws + OFF_H1);
    float* D    = ws + OFF_D;
    u16*   h2   = (u16*)(ws + OFF_H2);
    float* Ak   = ws + OFF_AK;
    u16*   Akh  = (u16*)(ws + OFF_AKH);
    u16*   Akl  = (u16*)(ws + OFF_AKL);
    u16*   AcT  = (u16*)(ws + OFF_ACT);
    u16*   Gb   = (u16*)(ws + OFF_GBF);
    u16*   W2a  = (u16*)(ws + OFF_W2A);
    u16*   W3b  = (u16*)(ws + OFF_W3B);
    unsigned* hist1 = (unsigned*)(ws + OFF_HIST);
    unsigned* sel   = (unsigned*)(ws + OFF_SEL);
    float* thr      = ws + OFF_THR;
    float* Ac       = ws + OFF_AC;

    k_build_mats<<<1024, 256, 0, stream>>>(Ak, Akh, Akl, AcT, Ac);
    k_zero<<<16, 256, 0, stream>>>(hist1, 4096);
    k_G_bf<<<1024, 256, 0, stream>>>(W1, Ak, Gb);
    k_wprep<<<2304, 256, 0, stream>>>(W2, W3, W2a, W3b);

    // forward spatial DCT (fp32) -> t NCHW
    k_tile_fwd<<<4096, 256, 0, stream>>>(x, t, Ac);
    // transpose + split to NHWC bf16 (t consumed -> region A reusable)
    k_tsplit<<<dim3(64, 8, 8), 256, 0, stream>>>(t, thi, tlo);
    // C-axis DCT via split-bf16 MFMA -> D fp32 NHWC (+ fused hist1)
    k_cgemm<<<dim3(4, 32, 8), 256, 0, stream>>>(thi, tlo, Akh, Akl, D, hist1);

    // exact top-k thresholds: LDS histograms + non-atomic privatized merge
    k_scan1<<<1, 256, 0, stream>>>(hist1, sel);
    k_hist2p<<<512, 256, 0, stream>>>((const float4*)D, sel, pA);
    k_red<<<16, 256, 0, stream>>>(pA, h2r, 4096, 512);
    k_scan2<<<1, 256, 0, stream>>>(h2r, sel);
    k_hist3p<<<512, 256, 0, stream>>>((const float4*)D, sel, pB);
    k_red<<<8, 256, 0, stream>>>(pB, h3r, 2048, 512);
    k_scan3<<<1, 256, 0, stream>>>(h3r, sel, thr);

    // branches (all 4 concurrent via grid.y)
    k_conv1<<<dim3(32, 4, 8), 256, 0, stream>>>(D, Gb, thr, h1pre);
    k_idct1<<<dim3(64, 4, 8), 256, 0, stream>>>(h1pre, AcT, X2);
    k_idct2<<<dim3(64, 4, 8), 256, 0, stream>>>(X2, AcT, b1, h1);
    k_conv2<<<dim3(32, 4, 8), 256, 0, stream>>>(h1, W2a, b2, h2);
    k_conv3<<<dim3(32, 4, 8), 256, 0, stream>>>(h2, W3b, b3, out);

    k_final<<<512, 256, 0, stream>>>(x, out);
}

// Round 6
// 673.692 us; speedup vs baseline: 99.0704x; 1.1962x over previous
//
#include <hip/hip_runtime.h>
#include <math.h>

#define NB   8
#define NC   512
#define SP   4096
#define TOT  16777216L
static const double PI_D = 3.14159265358979323846;

typedef short s16x8 __attribute__((ext_vector_type(8)));
typedef float f32x4 __attribute__((ext_vector_type(4)));
typedef unsigned short u16;

// ---------------- ws layout (float units) ----------------
// region A [0,16777216): t fp32; then selection scratch; then h1pre+X2 bf16
// region B [16777216,25165824): thi/tlo bf16; later h1 bf16
// region C [25165824,41943040): D fp32; later h2 bf16 in first half
#define OFF_T    0L
#define OFF_CAND 0L                   // u32[2048*4096] candidate slices (32 MB)
#define OFF_CNT  8388608L             // u32[2048] per-block counts
#define OFF_P2   8392704L             // u32[256*4096] hist2 partials
#define OFF_P3   9441280L             // u32[256*2048] hist3 partials
#define OFF_H2R  9965568L             // u32[4096] reduced hist2
#define OFF_H3R  9969664L             // u32[2048] reduced hist3
#define OFF_H1P  0L
#define OFF_X2   8388608L
#define OFF_THI  16777216L
#define OFF_TLO  20971520L
#define OFF_H1   16777216L
#define OFF_D    25165824L
#define OFF_H2   25165824L
#define OFF_AK   41943040L
#define OFF_AKH  42205184L
#define OFF_AKL  42336256L
#define OFF_ACT  42467328L
#define OFF_GBF  42468352L
#define OFF_W2A  42599424L
#define OFF_W3B  42894336L
#define OFF_HIST 42927104L            // hist1 4096 (u32)
#define OFF_SEL  42937344L            // u32[16]
#define OFF_THR  42937360L            // float[4]
#define OFF_AC   42937368L

__device__ inline u16 bfr(float x) {
    unsigned u = __float_as_uint(x);
    unsigned r = u + 0x7fffu + ((u >> 16) & 1u);
    return (u16)(r >> 16);
}
__device__ inline float bff(u16 h) { return __uint_as_float(((unsigned)h) << 16); }

#define MFMA(a, b, c) __builtin_amdgcn_mfma_f32_16x16x32_bf16((a), (b), (c), 0, 0, 0)

// ---------------- setup kernels ----------------
__global__ void k_build_mats(float* __restrict__ Ak, u16* __restrict__ Akh, u16* __restrict__ Akl,
                             u16* __restrict__ AcT, float* __restrict__ Ac) {
    int idx = blockIdx.x * 256 + threadIdx.x;
    if (idx < 512 * 512) {
        int i = idx >> 9, j = idx & 511;
        double v = cos((double)i * ((double)j + 0.5) * (PI_D / 512.0)) * sqrt(2.0 / 512.0);
        if (i == 0) v *= (1.0 / sqrt(2.0));
        float f = (float)v;
        Ak[idx] = f;
        u16 h = bfr(f);
        Akh[idx] = h;
        Akl[idx] = bfr(f - bff(h));
    }
    if (idx < 64 * 64) {
        int i = idx >> 6, j = idx & 63;
        double v = cos((double)i * ((double)j + 0.5) * (PI_D / 64.0)) * sqrt(2.0 / 64.0);
        if (i == 0) v *= (1.0 / sqrt(2.0));
        Ac[idx] = (float)v;
        int n = idx >> 6, np = idx & 63;
        double w = cos((double)np * ((double)n + 0.5) * (PI_D / 64.0)) * sqrt(2.0 / 64.0);
        if (np == 0) w *= (1.0 / sqrt(2.0));
        AcT[idx] = bfr((float)w);
    }
}

__global__ void k_zero(unsigned* __restrict__ p, int n) {
    int i = blockIdx.x * 256 + threadIdx.x;
    if (i < n) p[i] = 0u;
}

// G_bf[i][o][kc] = bf16( sum_c W1[i][o][c] * Ak[kc][c] )
__global__ void k_G_bf(const float* __restrict__ W1, const float* __restrict__ Ak,
                       u16* __restrict__ G) {
    int idx = blockIdx.x * 256 + threadIdx.x;
    int kc = idx & 511, oi = idx >> 9;
    const float* w = W1 + (long)oi * 512;
    const float* a = Ak + (long)kc * 512;
    float s = 0.f;
    for (int c = 0; c < 512; ++c) s += w[c] * a[c];
    G[idx] = bfr(s);
}

// W2a[i][o][t*128+ci] = W2[i][o][ci][t];  W3b = cvt(W3)
__global__ void k_wprep(const float* __restrict__ W2, const float* __restrict__ W3,
                        u16* __restrict__ W2a, u16* __restrict__ W3b) {
    int idx = blockIdx.x * 256 + threadIdx.x;
    if (idx < 4 * 128 * 1152) {
        int k = idx % 1152;
        int oi = idx / 1152;
        int t = k >> 7, ci = k & 127;
        W2a[idx] = bfr(W2[((long)oi * 128 + ci) * 9 + t]);
    }
    if (idx < 65536) W3b[idx] = bfr(W3[idx]);
}

// ---------------- forward 2D DCT tile (fp32) ----------------
__global__ __launch_bounds__(256) void k_tile_fwd(const float* __restrict__ in,
                                                  float* __restrict__ out,
                                                  const float* __restrict__ A64) {
    __shared__ __align__(16) float Ms[64][68];
    __shared__ __align__(16) float Ts[64][68];
    __shared__ __align__(16) float Ss[64][68];
    const int tid = threadIdx.x;
    const long tile = blockIdx.x;
    const float* __restrict__ src = in + tile * 4096;
    float* __restrict__ dst = out + tile * 4096;
    for (int idx = tid; idx < 4096; idx += 256) {
        int r = idx >> 6, c = idx & 63;
        Ms[c][r] = A64[idx];
        Ts[r][c] = src[idx];
    }
    __syncthreads();
    const int tx = tid & 15, ty = tid >> 4;
    float acc[4][4];
#pragma unroll
    for (int i = 0; i < 4; ++i)
#pragma unroll
        for (int j = 0; j < 4; ++j) acc[i][j] = 0.f;
#pragma unroll 4
    for (int j = 0; j < 64; ++j) {
        float4 bv = *(const float4*)&Ms[j][tx * 4];
        float a0 = Ts[ty * 4 + 0][j], a1 = Ts[ty * 4 + 1][j];
        float a2 = Ts[ty * 4 + 2][j], a3 = Ts[ty * 4 + 3][j];
        acc[0][0] += a0 * bv.x; acc[0][1] += a0 * bv.y; acc[0][2] += a0 * bv.z; acc[0][3] += a0 * bv.w;
        acc[1][0] += a1 * bv.x; acc[1][1] += a1 * bv.y; acc[1][2] += a1 * bv.z; acc[1][3] += a1 * bv.w;
        acc[2][0] += a2 * bv.x; acc[2][1] += a2 * bv.y; acc[2][2] += a2 * bv.z; acc[2][3] += a2 * bv.w;
        acc[3][0] += a3 * bv.x; acc[3][1] += a3 * bv.y; acc[3][2] += a3 * bv.z; acc[3][3] += a3 * bv.w;
    }
#pragma unroll
    for (int i = 0; i < 4; ++i)
        *(float4*)&Ss[ty * 4 + i][tx * 4] = make_float4(acc[i][0], acc[i][1], acc[i][2], acc[i][3]);
    __syncthreads();
#pragma unroll
    for (int i = 0; i < 4; ++i)
#pragma unroll
        for (int j = 0; j < 4; ++j) acc[i][j] = 0.f;
#pragma unroll 4
    for (int j = 0; j < 64; ++j) {
        float4 av = *(const float4*)&Ms[j][ty * 4];
        float4 sv = *(const float4*)&Ss[j][tx * 4];
        acc[0][0] += av.x * sv.x; acc[0][1] += av.x * sv.y; acc[0][2] += av.x * sv.z; acc[0][3] += av.x * sv.w;
        acc[1][0] += av.y * sv.x; acc[1][1] += av.y * sv.y; acc[1][2] += av.y * sv.z; acc[1][3] += av.y * sv.w;
        acc[2][0] += av.z * sv.x; acc[2][1] += av.z * sv.y; acc[2][2] += av.z * sv.z; acc[2][3] += av.z * sv.w;
        acc[3][0] += av.w * sv.x; acc[3][1] += av.w * sv.y; acc[3][2] += av.w * sv.z; acc[3][3] += av.w * sv.w;
    }
#pragma unroll
    for (int i = 0; i < 4; ++i)
        *(float4*)&dst[(ty * 4 + i) * 64 + tx * 4] = make_float4(acc[i][0], acc[i][1], acc[i][2], acc[i][3]);
}

// ---------------- transpose + split: t NCHW fp32 -> thi/tlo NHWC bf16 ----------------
__global__ __launch_bounds__(256) void k_tsplit(const float* __restrict__ t,
                                                u16* __restrict__ thi, u16* __restrict__ tlo) {
    __shared__ float Ls[64][65];
    const int b = blockIdx.z, cg = blockIdx.y, pg = blockIdx.x;
    const int tid = threadIdx.x;
    const float* src = t + ((long)b * 512 + cg * 64) * 4096 + pg * 64;
#pragma unroll
    for (int j = 0; j < 4; ++j) {
        int c = (tid >> 4) + j * 16, p4 = (tid & 15) * 4;
        float4 v = *(const float4*)&src[(long)c * 4096 + p4];
        Ls[c][p4 + 0] = v.x; Ls[c][p4 + 1] = v.y; Ls[c][p4 + 2] = v.z; Ls[c][p4 + 3] = v.w;
    }
    __syncthreads();
#pragma unroll
    for (int j = 0; j < 2; ++j) {
        int idx = tid + j * 256;
        int p = idx >> 3, c8 = idx & 7;
        s16x8 vh, vl;
#pragma unroll
        for (int q = 0; q < 8; ++q) {
            float f = Ls[c8 * 8 + q][p];
            u16 h = bfr(f);
            vh[q] = (short)h;
            vl[q] = (short)bfr(f - bff(h));
        }
        long addr = ((long)b * 4096 + pg * 64 + p) * 512 + cg * 64 + c8 * 8;
        *(s16x8*)&thi[addr] = vh;
        *(s16x8*)&tlo[addr] = vl;
    }
}

// ---------------- C-DCT GEMM + fused hist1 ----------------
__global__ __launch_bounds__(256, 2) void k_cgemm(const u16* __restrict__ thi, const u16* __restrict__ tlo,
                                                  const u16* __restrict__ Akh, const u16* __restrict__ Akl,
                                                  float* __restrict__ D, unsigned* __restrict__ g1) {
    __shared__ __align__(16) short Ph[128 * 40];
    __shared__ __align__(16) short Pl[128 * 40];
    __shared__ __align__(16) short Qh[128 * 40];
    __shared__ __align__(16) short Ql[128 * 40];
    __shared__ unsigned hh[4096];
    const int b = blockIdx.z;
    const int p0 = blockIdx.y * 128, kc0 = blockIdx.x * 128;
    const int tid = threadIdx.x;
    const int lane = tid & 63, wave = tid >> 6;
    const int fr = lane & 15, qd = lane >> 4;
    const int mq = (wave >> 1) * 64, nq = (wave & 1) * 64;
    for (int t = tid; t < 4096; t += 256) hh[t] = 0u;
    f32x4 acc[4][4];
#pragma unroll
    for (int i = 0; i < 4; ++i)
#pragma unroll
        for (int j = 0; j < 4; ++j) acc[i][j] = (f32x4){0.f, 0.f, 0.f, 0.f};
    const u16* Pgh = thi + ((long)b * 4096 + p0) * 512;
    const u16* Pgl = tlo + ((long)b * 4096 + p0) * 512;
    const u16* Qgh = Akh + (long)kc0 * 512;
    const u16* Qgl = Akl + (long)kc0 * 512;
    for (int ch = 0; ch < 16; ++ch) {
        const int k0 = ch * 32;
        __syncthreads();
#pragma unroll
        for (int j = 0; j < 2; ++j) {
            int idx = tid + j * 256;
            int r = idx >> 2, q4 = (idx & 3) * 8;
            *(s16x8*)&Ph[r * 40 + q4] = *(const s16x8*)&Pgh[(long)r * 512 + k0 + q4];
            *(s16x8*)&Pl[r * 40 + q4] = *(const s16x8*)&Pgl[(long)r * 512 + k0 + q4];
            *(s16x8*)&Qh[r * 40 + q4] = *(const s16x8*)&Qgh[(long)r * 512 + k0 + q4];
            *(s16x8*)&Ql[r * 40 + q4] = *(const s16x8*)&Qgl[(long)r * 512 + k0 + q4];
        }
        __syncthreads();
        s16x8 ph[4], pl[4], qh[4], ql[4];
#pragma unroll
        for (int i = 0; i < 4; ++i) {
            ph[i] = *(const s16x8*)&Ph[(mq + 16 * i + fr) * 40 + qd * 8];
            pl[i] = *(const s16x8*)&Pl[(mq + 16 * i + fr) * 40 + qd * 8];
            qh[i] = *(const s16x8*)&Qh[(nq + 16 * i + fr) * 40 + qd * 8];
            ql[i] = *(const s16x8*)&Ql[(nq + 16 * i + fr) * 40 + qd * 8];
        }
#pragma unroll
        for (int i = 0; i < 4; ++i)
#pragma unroll
            for (int j = 0; j < 4; ++j) {
                acc[i][j] = MFMA(ph[i], qh[j], acc[i][j]);
                acc[i][j] = MFMA(ph[i], ql[j], acc[i][j]);
                acc[i][j] = MFMA(pl[i], qh[j], acc[i][j]);
            }
    }
#pragma unroll
    for (int i = 0; i < 4; ++i)
#pragma unroll
        for (int j = 0; j < 4; ++j) {
            int rowb = mq + 16 * i + qd * 4;
            int col = kc0 + nq + 16 * j + fr;
#pragma unroll
            for (int r = 0; r < 4; ++r) {
                float v = acc[i][j][r];
                D[((long)b * 4096 + p0 + rowb + r) * 512 + col] = v;
                atomicAdd(&hh[__float_as_uint(fabsf(v)) >> 19], 1u);
            }
        }
    __syncthreads();
    for (int t = tid; t < 4096; t += 256) {
        unsigned c = hh[t];
        if (c) atomicAdd(&g1[t], c);
    }
}

// ---------------- selection ----------------
__global__ void k_scan1(const unsigned* __restrict__ hist, unsigned* __restrict__ sel) {
    __shared__ unsigned chunk[256];
    __shared__ unsigned above[256];
    const int t = threadIdx.x;
    unsigned s = 0;
#pragma unroll
    for (int j = 0; j < 16; ++j) s += hist[t * 16 + j];
    chunk[t] = s;
    __syncthreads();
    if (t == 0) {
        unsigned a = 0;
        for (int c = 255; c >= 0; --c) { above[c] = a; a += chunk[c]; }
    }
    __syncthreads();
    const unsigned kv[4] = {4194304u, 1048576u, 262144u, 65536u};
    unsigned run = above[t];
    for (int j = 15; j >= 0; --j) {
        unsigned bin = t * 16 + j;
        unsigned hb = hist[bin];
        unsigned Sab = run;
        run += hb;
#pragma unroll
        for (int i = 0; i < 4; ++i)
            if (run >= kv[i] && Sab < kv[i]) { sel[i] = bin; sel[4 + i] = kv[i] - Sab; }
    }
}

// single D pass: compact candidates (matching any selected prefix) into per-block
// private slices. LDS block counter + wave ballot; NO global atomics.
__global__ __launch_bounds__(256) void k_compact(const float4* __restrict__ D,
                                                 const unsigned* __restrict__ sel,
                                                 unsigned* __restrict__ cand,
                                                 unsigned* __restrict__ cnt) {
    __shared__ unsigned lctr;
    if (threadIdx.x == 0) lctr = 0u;
    __syncthreads();
    const unsigned p0 = sel[0], p1 = sel[1], p2 = sel[2], p3 = sel[3];
    const int lane = threadIdx.x & 63;
    unsigned* slice = cand + (long)blockIdx.x * 4096;
    const long n4 = TOT / 4;
    for (long idx = (long)blockIdx.x * 256 + threadIdx.x; idx < n4; idx += (long)gridDim.x * 256) {
        float4 v = D[idx];
        float f[4] = {v.x, v.y, v.z, v.w};
#pragma unroll
        for (int q = 0; q < 4; ++q) {
            unsigned u = __float_as_uint(fabsf(f[q]));
            unsigned pre = u >> 19;
            bool m = (pre == p0) | (pre == p1) | (pre == p2) | (pre == p3);
            unsigned long long mask = __ballot(m);
            if (mask) {
                int leader = __ffsll((long long)mask) - 1;
                unsigned base = 0;
                if (lane == leader) base = atomicAdd(&lctr, (unsigned)__popcll(mask));
                base = (unsigned)__shfl((int)base, leader);
                if (m) {
                    unsigned pos = base + (unsigned)__popcll(mask & ((1ULL << lane) - 1ULL));
                    if (pos < 4096u) slice[pos] = u;
                }
            }
        }
    }
    __syncthreads();
    if (threadIdx.x == 0) cnt[blockIdx.x] = lctr < 4096u ? lctr : 4096u;
}

// hist2 over candidates: mid-10 bits per selected prefix; privatized partials
__global__ __launch_bounds__(256) void k_hist2c(const unsigned* __restrict__ cand,
                                                const unsigned* __restrict__ cnt,
                                                const unsigned* __restrict__ sel,
                                                unsigned* __restrict__ partial) {
    __shared__ unsigned h[4096];
    for (int i = threadIdx.x; i < 4096; i += 256) h[i] = 0u;
    __syncthreads();
    const unsigned p0 = sel[0], p1 = sel[1], p2 = sel[2], p3 = sel[3];
    for (int s = 0; s < 8; ++s) {
        int slice = blockIdx.x * 8 + s;
        unsigned n = cnt[slice];
        const unsigned* L = cand + (long)slice * 4096;
        for (unsigned i = threadIdx.x; i < n; i += 256) {
            unsigned u = L[i];
            unsigned pre = u >> 19, mid = (u >> 9) & 1023u;
            if (pre == p0) atomicAdd(&h[mid], 1u);
            else if (pre == p1) atomicAdd(&h[1024 + mid], 1u);
            else if (pre == p2) atomicAdd(&h[2048 + mid], 1u);
            else if (pre == p3) atomicAdd(&h[3072 + mid], 1u);
        }
    }
    __syncthreads();
    unsigned* dst = partial + (long)blockIdx.x * 4096;
    for (int i = threadIdx.x; i < 4096; i += 256) dst[i] = h[i];
}

// reduce partial[nrows][nbins] -> out[nbins] (no atomics, coalesced)
__global__ __launch_bounds__(256) void k_red(const unsigned* __restrict__ partial,
                                             unsigned* __restrict__ out, int nbins, int nrows) {
    int bin = blockIdx.x * 256 + threadIdx.x;
    if (bin >= nbins) return;
    unsigned s = 0;
#pragma unroll 16
    for (int r = 0; r < nrows; ++r) s += partial[(long)r * nbins + bin];
    out[bin] = s;
}

__global__ void k_scan2(const unsigned* __restrict__ hist2, unsigned* __restrict__ sel) {
    __shared__ unsigned chunk[256];
    __shared__ unsigned above[256];
    const int t = threadIdx.x;
    for (int i = 0; i < 4; ++i) {
        const unsigned* h = hist2 + i * 1024;
        unsigned r = sel[4 + i];
        unsigned s = h[t * 4] + h[t * 4 + 1] + h[t * 4 + 2] + h[t * 4 + 3];
        chunk[t] = s;
        __syncthreads();
        if (t == 0) {
            unsigned a = 0;
            for (int c = 255; c >= 0; --c) { above[c] = a; a += chunk[c]; }
        }
        __syncthreads();
        unsigned run = above[t];
        for (int j = 3; j >= 0; --j) {
            unsigned bin = t * 4 + j;
            unsigned hb = h[bin];
            unsigned Sab = run;
            run += hb;
            if (run >= r && Sab < r) { sel[8 + i] = bin; sel[12 + i] = r - Sab; }
        }
        __syncthreads();
    }
}

// hist3 over candidates: low-9 bits for selected 22-bit prefixes
__global__ __launch_bounds__(256) void k_hist3c(const unsigned* __restrict__ cand,
                                                const unsigned* __restrict__ cnt,
                                                const unsigned* __restrict__ sel,
                                                unsigned* __restrict__ partial) {
    __shared__ unsigned h[2048];
    for (int i = threadIdx.x; i < 2048; i += 256) h[i] = 0u;
    __syncthreads();
    unsigned pre2[4];
#pragma unroll
    for (int i = 0; i < 4; ++i) pre2[i] = (sel[i] << 10) | sel[8 + i];
    for (int s = 0; s < 8; ++s) {
        int slice = blockIdx.x * 8 + s;
        unsigned n = cnt[slice];
        const unsigned* L = cand + (long)slice * 4096;
        for (unsigned i = threadIdx.x; i < n; i += 256) {
            unsigned u = L[i];
            unsigned p = u >> 9, low = u & 511u;
            if (p == pre2[0]) atomicAdd(&h[low], 1u);
            else if (p == pre2[1]) atomicAdd(&h[512 + low], 1u);
            else if (p == pre2[2]) atomicAdd(&h[1024 + low], 1u);
            else if (p == pre2[3]) atomicAdd(&h[1536 + low], 1u);
        }
    }
    __syncthreads();
    unsigned* dst = partial + (long)blockIdx.x * 2048;
    for (int i = threadIdx.x; i < 2048; i += 256) dst[i] = h[i];
}

__global__ void k_scan3(const unsigned* __restrict__ hist3, const unsigned* __restrict__ sel,
                        float* __restrict__ thr) {
    __shared__ unsigned chunk[256];
    __shared__ unsigned above[256];
    const int t = threadIdx.x;
    for (int i = 0; i < 4; ++i) {
        const unsigned* h = hist3 + i * 512;
        unsigned r = sel[12 + i];
        unsigned s = h[t * 2] + h[t * 2 + 1];
        chunk[t] = s;
        __syncthreads();
        if (t == 0) {
            unsigned a = 0;
            for (int c = 255; c >= 0; --c) { above[c] = a; a += chunk[c]; }
        }
        __syncthreads();
        unsigned run = above[t];
        for (int j = 1; j >= 0; --j) {
            unsigned bin = t * 2 + j;
            unsigned hb = h[bin];
            unsigned Sab = run;
            run += hb;
            if (run >= r && Sab < r)
                thr[i] = __uint_as_float((sel[i] << 19) | (sel[8 + i] << 9) | bin);
        }
        __syncthreads();
    }
}

// ---------------- conv1 fused with IDCT_C ----------------
__global__ __launch_bounds__(256, 2) void k_conv1(const float* __restrict__ D, const u16* __restrict__ Gb,
                                                  const float* __restrict__ thrp, u16* __restrict__ h1pre) {
    __shared__ __align__(16) short Pt[128 * 40];
    __shared__ __align__(16) short Qt[128 * 40];
    const int b = blockIdx.z, br = blockIdx.y, p0 = blockIdx.x * 128;
    const int z2 = br * 8 + b;
    const float thr = thrp[br];
    const int tid = threadIdx.x;
    const int lane = tid & 63, wave = tid >> 6;
    const int fr = lane & 15, qd = lane >> 4;
    const int mq = (wave >> 1) * 64, nq = (wave & 1) * 64;
    f32x4 acc[4][4];
#pragma unroll
    for (int i = 0; i < 4; ++i)
#pragma unroll
        for (int j = 0; j < 4; ++j) acc[i][j] = (f32x4){0.f, 0.f, 0.f, 0.f};
    const float* Pg = D + ((long)b * 4096 + p0) * 512;
    const u16* Qg = Gb + (long)br * 65536;
    for (int ch = 0; ch < 16; ++ch) {
        const int k0 = ch * 32;
        __syncthreads();
#pragma unroll
        for (int j = 0; j < 2; ++j) {
            int idx = tid + j * 256;
            int r = idx >> 2, q4 = (idx & 3) * 8;
            const float* src = &Pg[(long)r * 512 + k0 + q4];
            float4 v0 = *(const float4*)src;
            float4 v1 = *(const float4*)(src + 4);
            s16x8 m;
            float f[8] = {v0.x, v0.y, v0.z, v0.w, v1.x, v1.y, v1.z, v1.w};
#pragma unroll
            for (int q = 0; q < 8; ++q) m[q] = (short)(fabsf(f[q]) >= thr ? bfr(f[q]) : (u16)0);
            *(s16x8*)&Pt[r * 40 + q4] = m;
            *(s16x8*)&Qt[r * 40 + q4] = *(const s16x8*)&Qg[(long)r * 512 + k0 + q4];
        }
        __syncthreads();
        s16x8 pa[4], qb[4];
#pragma unroll
        for (int i = 0; i < 4; ++i) {
            pa[i] = *(const s16x8*)&Pt[(mq + 16 * i + fr) * 40 + qd * 8];
            qb[i] = *(const s16x8*)&Qt[(nq + 16 * i + fr) * 40 + qd * 8];
        }
#pragma unroll
        for (int i = 0; i < 4; ++i)
#pragma unroll
            for (int j = 0; j < 4; ++j) acc[i][j] = MFMA(pa[i], qb[j], acc[i][j]);
    }
#pragma unroll
    for (int i = 0; i < 4; ++i)
#pragma unroll
        for (int j = 0; j < 4; ++j) {
            int rowb = p0 + mq + 16 * i + qd * 4;
            int o = nq + 16 * j + fr;
            ushort4 pk;
            pk.x = bfr(acc[i][j][0]); pk.y = bfr(acc[i][j][1]);
            pk.z = bfr(acc[i][j][2]); pk.w = bfr(acc[i][j][3]);
            *(ushort4*)&h1pre[((long)z2 * 128 + o) * 4096 + rowb] = pk;
        }
}

// ---------------- IDCT passes ----------------
__global__ __launch_bounds__(256, 2) void k_idct1(const u16* __restrict__ h1pre, const u16* __restrict__ AcT,
                                                  u16* __restrict__ X2) {
    __shared__ __align__(16) short Pt[128 * 72];
    __shared__ __align__(16) short Qt[64 * 72];
    const int b = blockIdx.z, br = blockIdx.y, m0 = blockIdx.x * 128;
    const int z2 = br * 8 + b;
    const int tid = threadIdx.x;
    const int lane = tid & 63, wave = tid >> 6;
    const int fr = lane & 15, qd = lane >> 4;
    const int mq = wave * 32;
    const u16* Pg = h1pre + (long)z2 * 524288 + (long)m0 * 64;
    f32x4 acc[2][4];
#pragma unroll
    for (int i = 0; i < 2; ++i)
#pragma unroll
        for (int j = 0; j < 4; ++j) acc[i][j] = (f32x4){0.f, 0.f, 0.f, 0.f};
#pragma unroll
    for (int j = 0; j < 4; ++j) {
        int idx = tid + j * 256;
        int r = idx >> 3, q8 = (idx & 7) * 8;
        *(s16x8*)&Pt[r * 72 + q8] = *(const s16x8*)&Pg[(long)r * 64 + q8];
    }
#pragma unroll
    for (int j = 0; j < 2; ++j) {
        int idx = tid + j * 256;
        int r = idx >> 3, q8 = (idx & 7) * 8;
        *(s16x8*)&Qt[r * 72 + q8] = *(const s16x8*)&AcT[(long)r * 64 + q8];
    }
    __syncthreads();
#pragma unroll
    for (int ks = 0; ks < 2; ++ks) {
        s16x8 pa[2], qb[4];
#pragma unroll
        for (int i = 0; i < 2; ++i) pa[i] = *(const s16x8*)&Pt[(mq + 16 * i + fr) * 72 + ks * 32 + qd * 8];
#pragma unroll
        for (int j = 0; j < 4; ++j) qb[j] = *(const s16x8*)&Qt[(16 * j + fr) * 72 + ks * 32 + qd * 8];
#pragma unroll
        for (int i = 0; i < 2; ++i)
#pragma unroll
            for (int j = 0; j < 4; ++j) acc[i][j] = MFMA(pa[i], qb[j], acc[i][j]);
    }
#pragma unroll
    for (int i = 0; i < 2; ++i)
#pragma unroll
        for (int j = 0; j < 4; ++j) {
            int Rb = m0 + mq + 16 * i + qd * 4;
            int o = Rb >> 6, y = Rb & 63;
            int xo = 16 * j + fr;
            ushort4 pk;
            pk.x = bfr(acc[i][j][0]); pk.y = bfr(acc[i][j][1]);
            pk.z = bfr(acc[i][j][2]); pk.w = bfr(acc[i][j][3]);
            *(ushort4*)&X2[(long)z2 * 524288 + ((long)xo * 128 + o) * 64 + y] = pk;
        }
}

__global__ __launch_bounds__(256, 2) void k_idct2(const u16* __restrict__ X2, const u16* __restrict__ AcT,
                                                  const float* __restrict__ b1, u16* __restrict__ h1) {
    __shared__ __align__(16) short Pt[128 * 72];
    __shared__ __align__(16) short Qt[64 * 72];
    const int b = blockIdx.z, br = blockIdx.y, m0 = blockIdx.x * 128;
    const int z2 = br * 8 + b;
    const int tid = threadIdx.x;
    const int lane = tid & 63, wave = tid >> 6;
    const int fr = lane & 15, qd = lane >> 4;
    const int mq = wave * 32;
    const u16* Pg = X2 + (long)z2 * 524288 + (long)m0 * 64;
    f32x4 acc[2][4];
#pragma unroll
    for (int i = 0; i < 2; ++i)
#pragma unroll
        for (int j = 0; j < 4; ++j) acc[i][j] = (f32x4){0.f, 0.f, 0.f, 0.f};
#pragma unroll
    for (int j = 0; j < 4; ++j) {
        int idx = tid + j * 256;
        int r = idx >> 3, q8 = (idx & 7) * 8;
        *(s16x8*)&Pt[r * 72 + q8] = *(const s16x8*)&Pg[(long)r * 64 + q8];
    }
#pragma unroll
    for (int j = 0; j < 2; ++j) {
        int idx = tid + j * 256;
        int r = idx >> 3, q8 = (idx & 7) * 8;
        *(s16x8*)&Qt[r * 72 + q8] = *(const s16x8*)&AcT[(long)r * 64 + q8];
    }
    __syncthreads();
#pragma unroll
    for (int ks = 0; ks < 2; ++ks) {
        s16x8 pa[2], qb[4];
#pragma unroll
        for (int i = 0; i < 2; ++i) pa[i] = *(const s16x8*)&Pt[(mq + 16 * i + fr) * 72 + ks * 32 + qd * 8];
#pragma unroll
        for (int j = 0; j < 4; ++j) qb[j] = *(const s16x8*)&Qt[(16 * j + fr) * 72 + ks * 32 + qd * 8];
#pragma unroll
        for (int i = 0; i < 2; ++i)
#pragma unroll
            for (int j = 0; j < 4; ++j) acc[i][j] = MFMA(pa[i], qb[j], acc[i][j]);
    }
#pragma unroll
    for (int i = 0; i < 2; ++i)
#pragma unroll
        for (int j = 0; j < 4; ++j) {
            int Rb = m0 + mq + 16 * i + qd * 4;
            int xo = Rb >> 7, o = Rb & 127;
            int yo = 16 * j + fr;
            ushort4 pk;
            const float* bg = b1 + br * 128 + o;
            pk.x = bfr(fmaxf(acc[i][j][0] + bg[0], 0.f));
            pk.y = bfr(fmaxf(acc[i][j][1] + bg[1], 0.f));
            pk.z = bfr(fmaxf(acc[i][j][2] + bg[2], 0.f));
            pk.w = bfr(fmaxf(acc[i][j][3] + bg[3], 0.f));
            *(ushort4*)&h1[(long)z2 * 524288 + ((long)yo * 64 + xo) * 128 + o] = pk;
        }
}

// ---------------- conv2: implicit GEMM ----------------
__global__ __launch_bounds__(256, 2) void k_conv2(const u16* __restrict__ h1, const u16* __restrict__ W2a,
                                                  const float* __restrict__ b2, u16* __restrict__ h2) {
    __shared__ __align__(16) short Pt[128 * 40];
    __shared__ __align__(16) short Qt[128 * 40];
    const int b = blockIdx.z, br = blockIdx.y, y0 = blockIdx.x * 2;
    const int z2 = br * 8 + b;
    const int tid = threadIdx.x;
    const int lane = tid & 63, wave = tid >> 6;
    const int fr = lane & 15, qd = lane >> 4;
    const int mq = (wave >> 1) * 64, nq = (wave & 1) * 64;
    f32x4 acc[4][4];
#pragma unroll
    for (int i = 0; i < 4; ++i)
#pragma unroll
        for (int j = 0; j < 4; ++j) acc[i][j] = (f32x4){0.f, 0.f, 0.f, 0.f};
    const u16* hb = h1 + (long)z2 * 524288;
    const u16* Qg = W2a + (long)br * 147456;
    for (int ch = 0; ch < 36; ++ch) {
        const int t9 = ch >> 2, ci0 = (ch & 3) * 32;
        const int ky = t9 / 3, kx = t9 - 3 * ky;
        const int dy = 2 * ky - 2, dx = 2 * kx - 2;
        __syncthreads();
#pragma unroll
        for (int j = 0; j < 2; ++j) {
            int idx = tid + j * 256;
            int r = idx >> 2, q4 = (idx & 3) * 8;
            int ry = r >> 6, x = r & 63;
            int ysrc = y0 + ry + dy, xsrc = x + dx;
            s16x8 v = {0, 0, 0, 0, 0, 0, 0, 0};
            if ((unsigned)ysrc < 64u && (unsigned)xsrc < 64u)
                v = *(const s16x8*)&hb[((long)ysrc * 64 + xsrc) * 128 + ci0 + q4];
            *(s16x8*)&Pt[r * 40 + q4] = v;
            *(s16x8*)&Qt[r * 40 + q4] = *(const s16x8*)&Qg[(long)r * 1152 + ch * 32 + q4];
        }
        __syncthreads();
        s16x8 pa[4], qb[4];
#pragma unroll
        for (int i = 0; i < 4; ++i) {
            pa[i] = *(const s16x8*)&Pt[(mq + 16 * i + fr) * 40 + qd * 8];
            qb[i] = *(const s16x8*)&Qt[(nq + 16 * i + fr) * 40 + qd * 8];
        }
#pragma unroll
        for (int i = 0; i < 4; ++i)
#pragma unroll
            for (int j = 0; j < 4; ++j) acc[i][j] = MFMA(pa[i], qb[j], acc[i][j]);
    }
#pragma unroll
    for (int i = 0; i < 4; ++i)
#pragma unroll
        for (int j = 0; j < 4; ++j) {
            int rowb = mq + 16 * i + qd * 4;
            int o = nq + 16 * j + fr;
            float bb = b2[br * 128 + o];
#pragma unroll
            for (int r = 0; r < 4; ++r) {
                float v = fmaxf(acc[i][j][r] + bb, 0.f);
                h2[(long)z2 * 524288 + ((long)y0 * 64 + rowb + r) * 128 + o] = bfr(v);
            }
        }
}

// ---------------- conv3 ----------------
__global__ __launch_bounds__(256, 2) void k_conv3(const u16* __restrict__ h2, const u16* __restrict__ W3b,
                                                  const float* __restrict__ b3, float* __restrict__ out) {
    __shared__ __align__(16) short Pt[128 * 40];
    __shared__ __align__(16) short Qt[128 * 40];
    const int b = blockIdx.z, br = blockIdx.y, p0 = blockIdx.x * 128;
    const int z2 = br * 8 + b;
    const int tid = threadIdx.x;
    const int lane = tid & 63, wave = tid >> 6;
    const int fr = lane & 15, qd = lane >> 4;
    const int mq = (wave >> 1) * 64, nq = (wave & 1) * 64;
    f32x4 acc[4][4];
#pragma unroll
    for (int i = 0; i < 4; ++i)
#pragma unroll
        for (int j = 0; j < 4; ++j) acc[i][j] = (f32x4){0.f, 0.f, 0.f, 0.f};
    const u16* Pg = h2 + (long)z2 * 524288 + (long)p0 * 128;
    const u16* Qg = W3b + (long)br * 16384;
    for (int ch = 0; ch < 4; ++ch) {
        const int k0 = ch * 32;
        __syncthreads();
#pragma unroll
        for (int j = 0; j < 2; ++j) {
            int idx = tid + j * 256;
            int r = idx >> 2, q4 = (idx & 3) * 8;
            *(s16x8*)&Pt[r * 40 + q4] = *(const s16x8*)&Pg[(long)r * 128 + k0 + q4];
            *(s16x8*)&Qt[r * 40 + q4] = *(const s16x8*)&Qg[(long)r * 128 + k0 + q4];
        }
        __syncthreads();
        s16x8 pa[4], qb[4];
#pragma unroll
        for (int i = 0; i < 4; ++i) {
            pa[i] = *(const s16x8*)&Pt[(mq + 16 * i + fr) * 40 + qd * 8];
            qb[i] = *(const s16x8*)&Qt[(nq + 16 * i + fr) * 40 + qd * 8];
        }
#pragma unroll
        for (int i = 0; i < 4; ++i)
#pragma unroll
            for (int j = 0; j < 4; ++j) acc[i][j] = MFMA(pa[i], qb[j], acc[i][j]);
    }
#pragma unroll
    for (int i = 0; i < 4; ++i)
#pragma unroll
        for (int j = 0; j < 4; ++j) {
            int rowb = mq + 16 * i + qd * 4;
            int o = nq + 16 * j + fr;
            float bb = b3[br * 128 + o];
            float4 v = make_float4(fmaxf(acc[i][j][0] + bb, 0.f), fmaxf(acc[i][j][1] + bb, 0.f),
                                   fmaxf(acc[i][j][2] + bb, 0.f), fmaxf(acc[i][j][3] + bb, 0.f));
            *(float4*)&out[((long)b * 512 + br * 128 + o) * 4096 + p0 + rowb] = v;
        }
}

// ---------------- softmax gating + residual ----------------
__global__ __launch_bounds__(256) void k_final(const float* __restrict__ x, float* __restrict__ io) {
    const int bm = blockIdx.x;
    const int b = bm >> 6, m = bm & 63;
    const int n = threadIdx.x & 63, grp = threadIdx.x >> 6;
    const long base = ((long)b * 512) * 4096 + m * 64 + n;
    __shared__ float red[4][64];
    float mx = -1e30f;
    for (int c = grp * 128; c < grp * 128 + 128; ++c)
        mx = fmaxf(mx, io[base + (long)c * 4096]);
    red[grp][n] = mx;
    __syncthreads();
    const float M = fmaxf(fmaxf(red[0][n], red[1][n]), fmaxf(red[2][n], red[3][n]));
    __syncthreads();
    float s = 0.f;
    for (int c = grp * 128; c < grp * 128 + 128; ++c)
        s += __expf(io[base + (long)c * 4096] - M);
    red[grp][n] = s;
    __syncthreads();
    const float S = red[0][n] + red[1][n] + red[2][n] + red[3][n];
    const float inv = 1.0f / S;
    for (int c = grp * 128; c < grp * 128 + 128; ++c) {
        long a = base + (long)c * 4096;
        float w = __expf(io[a] - M) * inv;
        float xv = x[a];
        io[a] = xv * w + xv;
    }
}

// ---------------------------------------------------------------------------
extern "C" void kernel_launch(void* const* d_in, const int* in_sizes, int n_in,
                              void* d_out, int out_size, void* d_ws, size_t ws_size,
                              hipStream_t stream) {
    (void)in_sizes; (void)n_in; (void)out_size; (void)ws_size;
    const float* x  = (const float*)d_in[0];
    const float* W1 = (const float*)d_in[1];
    const float* b1 = (const float*)d_in[2];
    const float* W2 = (const float*)d_in[3];
    const float* b2 = (const float*)d_in[4];
    const float* W3 = (const float*)d_in[5];
    const float* b3 = (const float*)d_in[6];
    float* out = (float*)d_out;
    float* ws = (float*)d_ws;

    float* t    = ws + OFF_T;
    unsigned* cand = (unsigned*)(ws + OFF_CAND);
    unsigned* cnt  = (unsigned*)(ws + OFF_CNT);
    unsigned* p2   = (unsigned*)(ws + OFF_P2);
    unsigned* p3   = (unsigned*)(ws + OFF_P3);
    unsigned* h2r  = (unsigned*)(ws + OFF_H2R);
    unsigned* h3r  = (unsigned*)(ws + OFF_H3R);
    u16*   h1pre= (u16*)(ws + OFF_H1P);
    u16*   X2   = (u16*)(ws + OFF_X2);
    u16*   thi  = (u16*)(ws + OFF_THI);
    u16*   tlo  = (u16*)(ws + OFF_TLO);
    u16*   h1   = (u16*)(ws + OFF_H1);
    float* D    = ws + OFF_D;
    u16*   h2   = (u16*)(ws + OFF_H2);
    float* Ak   = ws + OFF_AK;
    u16*   Akh  = (u16*)(ws + OFF_AKH);
    u16*   Akl  = (u16*)(ws + OFF_AKL);
    u16*   AcT  = (u16*)(ws + OFF_ACT);
    u16*   Gb   = (u16*)(ws + OFF_GBF);
    u16*   W2a  = (u16*)(ws + OFF_W2A);
    u16*   W3b  = (u16*)(ws + OFF_W3B);
    unsigned* hist1 = (unsigned*)(ws + OFF_HIST);
    unsigned* sel   = (unsigned*)(ws + OFF_SEL);
    float* thr      = ws + OFF_THR;
    float* Ac       = ws + OFF_AC;

    k_build_mats<<<1024, 256, 0, stream>>>(Ak, Akh, Akl, AcT, Ac);
    k_zero<<<16, 256, 0, stream>>>(hist1, 4096);
    k_G_bf<<<1024, 256, 0, stream>>>(W1, Ak, Gb);
    k_wprep<<<2304, 256, 0, stream>>>(W2, W3, W2a, W3b);

    // forward spatial DCT (fp32) -> t NCHW
    k_tile_fwd<<<4096, 256, 0, stream>>>(x, t, Ac);
    // transpose + split to NHWC bf16 (t consumed -> region A reusable)
    k_tsplit<<<dim3(64, 8, 8), 256, 0, stream>>>(t, thi, tlo);
    // C-axis DCT via split-bf16 MFMA -> D fp32 NHWC (+ fused hist1)
    k_cgemm<<<dim3(4, 32, 8), 256, 0, stream>>>(thi, tlo, Akh, Akl, D, hist1);

    // exact top-k thresholds: one compact pass over D, then candidate-local refine
    k_scan1<<<1, 256, 0, stream>>>(hist1, sel);
    k_compact<<<2048, 256, 0, stream>>>((const float4*)D, sel, cand, cnt);
    k_hist2c<<<256, 256, 0, stream>>>(cand, cnt, sel, p2);
    k_red<<<16, 256, 0, stream>>>(p2, h2r, 4096, 256);
    k_scan2<<<1, 256, 0, stream>>>(h2r, sel);
    k_hist3c<<<256, 256, 0, stream>>>(cand, cnt, sel, p3);
    k_red<<<8, 256, 0, stream>>>(p3, h3r, 2048, 256);
    k_scan3<<<1, 256, 0, stream>>>(h3r, sel, thr);

    // branches (all 4 concurrent via grid.y)
    k_conv1<<<dim3(32, 4, 8), 256, 0, stream>>>(D, Gb, thr, h1pre);
    k_idct1<<<dim3(64, 4, 8), 256, 0, stream>>>(h1pre, AcT, X2);
    k_idct2<<<dim3(64, 4, 8), 256, 0, stream>>>(X2, AcT, b1, h1);
    k_conv2<<<dim3(32, 4, 8), 256, 0, stream>>>(h1, W2a, b2, h2);
    k_conv3<<<dim3(32, 4, 8), 256, 0, stream>>>(h2, W3b, b3, out);

    k_final<<<512, 256, 0, stream>>>(x, out);
}